// Round 17
// baseline (235.918 us; speedup 1.0000x reference)
//
#include <hip/hip_runtime.h>
#include <hip/hip_bf16.h>
#include <stdint.h>

typedef __attribute__((ext_vector_type(8))) short bf16x8;
typedef __attribute__((ext_vector_type(8))) unsigned short u16x8;
typedef __attribute__((ext_vector_type(4))) float f32x4;
typedef __attribute__((ext_vector_type(4))) unsigned short u16x4;

#define T_SEQ 2048
#define HID_D 2880
#define KPAD 2944              // 2880 padded to 46*64
#define NH 64
#define NKV 8
#define HD 64
#define QKV_N 5120
#define ATT_N 4096
#define NOPAD 3072             // wo_bf region rows (layout constant)
#define WIN 128
#define RSCALE 0.125f
#define MSCALE 1.3465735903f
#define ROPE_TOT (T_SEQ * (NH + NKV) * 32)   // 4718592
#define ROPE_BLKS (ROPE_TOT / 256)           // 18432

__device__ __forceinline__ unsigned short f2bf(float f) {
  union { float f; unsigned u; } v; v.f = f;
  unsigned r = v.u + 0x7fffu + ((v.u >> 16) & 1u);
  return (unsigned short)(r >> 16);
}
__device__ __forceinline__ float bf2f(unsigned short u) {
  union { unsigned u; float f; } v; v.u = ((unsigned)u) << 16;
  return v.f;
}

__device__ __forceinline__ void gload_lds16(const void* g, void* l) {
  __builtin_amdgcn_global_load_lds((const __attribute__((address_space(1))) char*)g,
                                   (__attribute__((address_space(3))) char*)l, 16, 0, 0);
}

#define GPH_MID()                                        \
  __builtin_amdgcn_s_barrier();                          \
  asm volatile("s_waitcnt lgkmcnt(0)" ::: "memory");     \
  __builtin_amdgcn_sched_barrier(0);                     \
  __builtin_amdgcn_s_setprio(1)
#define GPH_END()                                        \
  __builtin_amdgcn_s_setprio(0);                         \
  __builtin_amdgcn_s_barrier()

// ---------------- fused RMSNorm (blocks 0..2047) + w_qkv->bf16 pad (blocks 2048..3071) ----------------
__global__ __launch_bounds__(256) void pre_kernel(const float* __restrict__ x,
                                                  const float* __restrict__ w,
                                                  unsigned short* __restrict__ t_bf,
                                                  const float* __restrict__ wq_src,
                                                  unsigned short* __restrict__ wq_dst) {
  __shared__ float red[256];
  if (blockIdx.x < 2048) {
    int row = blockIdx.x;
    const float4* xr4 = (const float4*)(x + (size_t)row * HID_D);
    const float4* w4 = (const float4*)w;
    float ss = 0.f;
    for (int i = threadIdx.x; i < 720; i += 256) {
      float4 v = xr4[i];
      ss += v.x * v.x + v.y * v.y + v.z * v.z + v.w * v.w;
    }
    red[threadIdx.x] = ss;
    __syncthreads();
    for (int s = 128; s > 0; s >>= 1) {
      if (threadIdx.x < s) red[threadIdx.x] += red[threadIdx.x + s];
      __syncthreads();
    }
    float rs = rsqrtf(red[0] / (float)HID_D + 1e-5f);
    u16x4* ob = (u16x4*)(t_bf + (size_t)row * KPAD);
    for (int i = threadIdx.x; i < 736; i += 256) {
      u16x4 o = {0, 0, 0, 0};
      if (i < 720) {
        float4 v = xr4[i];
        float4 g = w4[i];
        o = { f2bf(v.x * rs * g.x), f2bf(v.y * rs * g.y),
              f2bf(v.z * rs * g.z), f2bf(v.w * rs * g.w) };
      }
      ob[i] = o;
    }
  } else {
    const int total = QKV_N * 736;
    for (int i = (blockIdx.x - 2048) * 256 + threadIdx.x; i < total; i += 1024 * 256) {
      int c4 = i % 736, row = i / 736;
      u16x4 o = {0, 0, 0, 0};
      if (c4 < 720) {
        float4 v = ((const float4*)wq_src)[(size_t)row * 720 + c4];
        o = { f2bf(v.x), f2bf(v.y), f2bf(v.z), f2bf(v.w) };
      }
      ((u16x4*)wq_dst)[i] = o;
    }
  }
}

// ============ QKV GEMM: 128x320 tile, 256 blocks (16Mx16N), FULL K=2944 ============
__global__ __launch_bounds__(512, 2) void qkv320_kernel(const unsigned short* __restrict__ A,
                                                        const unsigned short* __restrict__ B,
                                                        unsigned short* __restrict__ C,
                                                        const float* __restrict__ bias) {
  __shared__ unsigned short sA[2 * 128 * 64];       // 32 KiB
  __shared__ unsigned short sB[3 * 320 * 64];       // 120 KiB

  const int tid = threadIdx.x;
  const int lane = tid & 63, wid = tid >> 6;
  const int wr = wid >> 2, wc = wid & 3;            // 2M x 4N waves: 64x80 each
  const int lq = lane & 15, ro = lane >> 4;

  const int c = blockIdx.x & 7, q = blockIdx.x >> 3;      // q: 0..31
  const int by = (c & 1) * 8 + (q & 7);
  const int bx = (c >> 1) * 4 + (q >> 3);
  const int m0 = by * 128, n0 = bx * 320;

  const int R0 = tid >> 3;
  const int g0 = (((tid & 7) ^ (R0 & 7)) << 3);
  const size_t aOff = (size_t)(m0 + R0) * KPAD + g0;
  size_t bOff[5];
#pragma unroll
  for (int r = 0; r < 5; ++r)
    bOff[r] = (size_t)(n0 + r * 64 + R0) * KPAD + g0;

  const int ck0 = ((ro ^ (lq & 7)) << 3);
  const int ck1 = (((4 + ro) ^ (lq & 7)) << 3);

#define QSTG_A(BUF, KT)                                                         \
  { unsigned short* _d = sA + (BUF) * 8192 + wid * 512;                         \
    const unsigned short* _s = A + aOff + (size_t)(KT) * 64;                    \
    gload_lds16(_s, _d); gload_lds16(_s + (size_t)64 * KPAD, _d + 4096); }
#define QSTG_B(BUF, KT)                                                         \
  { unsigned short* _d = sB + (BUF) * 20480 + wid * 512;                        \
    gload_lds16(B + bOff[0] + (KT) * 64, _d);                                   \
    gload_lds16(B + bOff[1] + (KT) * 64, _d + 4096);                            \
    gload_lds16(B + bOff[2] + (KT) * 64, _d + 8192);                            \
    gload_lds16(B + bOff[3] + (KT) * 64, _d + 12288);                           \
    gload_lds16(B + bOff[4] + (KT) * 64, _d + 16384); }

  bf16x8 aR[8];
  bf16x8 b00, b01, b10, b11, b20, b21, b30, b31, b40, b41;
  f32x4 acc[4][5] = {};

#define QLDA(BUF)                                                                          \
  { _Pragma("unroll") for (int ii = 0; ii < 4; ++ii) {                                     \
      const int _r = (BUF) * 8192 + (wr * 64 + ii * 16 + lq) * 64;                         \
      aR[ii * 2 + 0] = *(const bf16x8*)&sA[_r + ck0];                                      \
      aR[ii * 2 + 1] = *(const bf16x8*)&sA[_r + ck1]; } }
#define QLDB(BUF, J, D0, D1)                                                               \
  { const int _r = (BUF) * 20480 + (wc * 80 + (J) * 16 + lq) * 64;                         \
    D0 = *(const bf16x8*)&sB[_r + ck0];                                                    \
    D1 = *(const bf16x8*)&sB[_r + ck1]; }
#define QMM(J, B0, B1)                                                                     \
  { _Pragma("unroll") for (int ii = 0; ii < 4; ++ii) {                                     \
      acc[ii][J] = __builtin_amdgcn_mfma_f32_16x16x32_bf16(aR[ii * 2 + 0], B0, acc[ii][J], 0, 0, 0); \
      acc[ii][J] = __builtin_amdgcn_mfma_f32_16x16x32_bf16(aR[ii * 2 + 1], B1, acc[ii][J], 0, 0, 0); } }

  QSTG_B(0, 0); QSTG_A(0, 0);
  QSTG_B(1, 1); QSTG_A(1, 1);
  asm volatile("s_waitcnt vmcnt(7)" ::: "memory");
  __builtin_amdgcn_s_barrier();

  const int nt = 46;
  for (int T = 0; T < nt; ++T) {
    const bool more = (T + 2 < nt);
    const int bb = T % 3, bA = T & 1;
    QLDA(bA);
    QLDB(bb, 0, b00, b01);
    QLDB(bb, 1, b10, b11);
    if (more) QSTG_B((T + 2) % 3, T + 2);
    GPH_MID();
    QMM(0, b00, b01);
    QMM(1, b10, b11);
    GPH_END();
    QLDB(bb, 2, b20, b21);
    QLDB(bb, 3, b30, b31);
    QLDB(bb, 4, b40, b41);
    if (more) QSTG_A((T + 2) & 1, T + 2);
    GPH_MID();
    QMM(2, b20, b21);
    QMM(3, b30, b31);
    QMM(4, b40, b41);
    __builtin_amdgcn_s_setprio(0);
    if (more) asm volatile("s_waitcnt vmcnt(7)" ::: "memory");
    else      asm volatile("s_waitcnt vmcnt(0)" ::: "memory");
    __builtin_amdgcn_s_barrier();
  }
#undef QSTG_A
#undef QSTG_B
#undef QLDA
#undef QLDB
#undef QMM

#pragma unroll
  for (int ii = 0; ii < 4; ++ii) {
    const int gr = m0 + wr * 64 + ii * 16 + ro * 4;
#pragma unroll
    for (int j = 0; j < 5; ++j) {
      const int gc = n0 + wc * 80 + j * 16 + lq;
      const float bv = bias[gc];
#pragma unroll
      for (int r = 0; r < 4; ++r)
        C[(size_t)(gr + r) * QKV_N + gc] = f2bf(acc[ii][j][r] + bv);
    }
  }
}

// ============ out projection: 128x192 tile, BK=64, SINGLE-PHASE, 2-buf (80 KB -> 2 blocks/CU) ============
// Depth-1 prefetch: stage T+1 into buf (T+1)&1 (readers done at end-of-(T-1) barrier);
// drain vmcnt(0) before end-of-T barrier (T's MFMA covers the HBM latency).
// Row pitch 64 elems -> proven 3-bit XOR swizzle (conflict-free).
__global__ __launch_bounds__(512, 2) void outproj192_kernel(const unsigned short* __restrict__ att,
                                                            const unsigned short* __restrict__ wo,
                                                            float* __restrict__ out,
                                                            const float* __restrict__ b_o,
                                                            const float* __restrict__ x) {
  __shared__ unsigned short sA[2 * 128 * 64];       // 32 KiB
  __shared__ unsigned short sB[2 * 192 * 64];       // 48 KiB

  const int tid = threadIdx.x;
  const int lane = tid & 63, wid = tid >> 6;
  const int wr = wid >> 2, wc = wid & 3;            // 2M x 4N waves: 64x48 each
  const int lq = lane & 15, ro = lane >> 4;

  const int c = blockIdx.x & 7, q = blockIdx.x >> 3;      // q: 0..29
  const int by = c * 2 + (q >= 15 ? 1 : 0);
  const int bx = (q >= 15) ? q - 15 : q;
  const int m0 = by * 128, n0 = bx * 192;

  const int R0 = tid >> 3;
  const int g0 = (((tid & 7) ^ (R0 & 7)) << 3);
  const size_t aOff = (size_t)(m0 + R0) * ATT_N + g0;
  size_t bOff[3];
#pragma unroll
  for (int r = 0; r < 3; ++r)
    bOff[r] = (size_t)(n0 + r * 64 + R0) * ATT_N + g0;

  const int ck0 = ((ro ^ (lq & 7)) << 3);
  const int ck1 = (((4 + ro) ^ (lq & 7)) << 3);

#define PSTG_A(BUF, KT)                                                         \
  { unsigned short* _d = sA + (BUF) * 8192 + wid * 512;                         \
    const unsigned short* _s = att + aOff + (size_t)(KT) * 64;                  \
    gload_lds16(_s, _d); gload_lds16(_s + (size_t)64 * ATT_N, _d + 4096); }
#define PSTG_B(BUF, KT)                                                         \
  { unsigned short* _d = sB + (BUF) * 12288 + wid * 512;                        \
    gload_lds16(wo + bOff[0] + (KT) * 64, _d);                                  \
    gload_lds16(wo + bOff[1] + (KT) * 64, _d + 4096);                           \
    gload_lds16(wo + bOff[2] + (KT) * 64, _d + 8192); }

  bf16x8 aR[8];
  bf16x8 b00, b01, b10, b11, b20, b21;
  f32x4 acc[4][3] = {};

#define PLDA(BUF)                                                                          \
  { _Pragma("unroll") for (int ii = 0; ii < 4; ++ii) {                                     \
      const int _r = (BUF) * 8192 + (wr * 64 + ii * 16 + lq) * 64;                         \
      aR[ii * 2 + 0] = *(const bf16x8*)&sA[_r + ck0];                                      \
      aR[ii * 2 + 1] = *(const bf16x8*)&sA[_r + ck1]; } }
#define PLDB(BUF, J, D0, D1)                                                               \
  { const int _r = (BUF) * 12288 + (wc * 48 + (J) * 16 + lq) * 64;                         \
    D0 = *(const bf16x8*)&sB[_r + ck0];                                                    \
    D1 = *(const bf16x8*)&sB[_r + ck1]; }

  // prologue: tile 0 into buf 0
  PSTG_B(0, 0); PSTG_A(0, 0);
  asm volatile("s_waitcnt vmcnt(0)" ::: "memory");
  __builtin_amdgcn_s_barrier();

  const int nt = 64;
  for (int T = 0; T < nt; ++T) {
    const int bb = T & 1;
    if (T + 1 < nt) { PSTG_B(bb ^ 1, T + 1); PSTG_A(bb ^ 1, T + 1); }
    PLDA(bb);
    PLDB(bb, 0, b00, b01);
    PLDB(bb, 1, b10, b11);
    PLDB(bb, 2, b20, b21);
    asm volatile("s_waitcnt lgkmcnt(0)" ::: "memory");
    __builtin_amdgcn_sched_barrier(0);
    __builtin_amdgcn_s_setprio(1);
#pragma unroll
    for (int ii = 0; ii < 4; ++ii) {
      acc[ii][0] = __builtin_amdgcn_mfma_f32_16x16x32_bf16(aR[ii * 2 + 0], b00, acc[ii][0], 0, 0, 0);
      acc[ii][0] = __builtin_amdgcn_mfma_f32_16x16x32_bf16(aR[ii * 2 + 1], b01, acc[ii][0], 0, 0, 0);
      acc[ii][1] = __builtin_amdgcn_mfma_f32_16x16x32_bf16(aR[ii * 2 + 0], b10, acc[ii][1], 0, 0, 0);
      acc[ii][1] = __builtin_amdgcn_mfma_f32_16x16x32_bf16(aR[ii * 2 + 1], b11, acc[ii][1], 0, 0, 0);
      acc[ii][2] = __builtin_amdgcn_mfma_f32_16x16x32_bf16(aR[ii * 2 + 0], b20, acc[ii][2], 0, 0, 0);
      acc[ii][2] = __builtin_amdgcn_mfma_f32_16x16x32_bf16(aR[ii * 2 + 1], b21, acc[ii][2], 0, 0, 0);
    }
    __builtin_amdgcn_s_setprio(0);
    asm volatile("s_waitcnt vmcnt(0)" ::: "memory");
    __builtin_amdgcn_s_barrier();
  }
#undef PSTG_A
#undef PSTG_B
#undef PLDA
#undef PLDB

#pragma unroll
  for (int ii = 0; ii < 4; ++ii) {
    const int gr = m0 + wr * 64 + ii * 16 + ro * 4;
#pragma unroll
    for (int j = 0; j < 3; ++j) {
      const int gc = n0 + wc * 48 + j * 16 + lq;
      const float bv = b_o[gc];
#pragma unroll
      for (int r = 0; r < 4; ++r) {
        size_t off = (size_t)(gr + r) * HID_D + gc;
        out[off] = acc[ii][j][r] + bv + x[off];
      }
    }
  }
}

// ---------------- fused YaRN RoPE (blocks 0..18431) + V transpose (blocks 18432..18687) ----------------
__global__ __launch_bounds__(256) void ropevt_kernel(const unsigned short* __restrict__ qkvb,
                                                     const int* __restrict__ positions,
                                                     unsigned short* __restrict__ qb,
                                                     unsigned short* __restrict__ kb,
                                                     unsigned short* __restrict__ vt) {
  __shared__ unsigned short tile[64][72];
  if (blockIdx.x >= ROPE_BLKS) {
    const int vb = blockIdx.x - ROPE_BLKS;
    const int g = vb >> 5;
    const int t0 = (vb & 31) << 6;
    const int r = threadIdx.x >> 3;
    const int c8 = (threadIdx.x & 7) << 3;
    const size_t vbase = (size_t)(NH + NKV) * HD + (size_t)g * HD;
#pragma unroll
    for (int hh = 0; hh < 2; ++hh) {
      int row = r + hh * 32;
      *(u16x8*)&tile[row][c8] =
          *(const u16x8*)(qkvb + (size_t)(t0 + row) * QKV_N + vbase + c8);
    }
    __syncthreads();
    const int d = threadIdx.x >> 2;
    const int ts = (threadIdx.x & 3) << 4;
    u16x8 v0, v1;
#pragma unroll
    for (int i = 0; i < 8; ++i) { v0[i] = tile[ts + i][d]; v1[i] = tile[ts + 8 + i][d]; }
    unsigned short* dst = vt + (size_t)(g * HD + d) * T_SEQ + t0 + ts;
    *(u16x8*)dst = v0;
    *(u16x8*)(dst + 8) = v1;
    return;
  }
  int idx = blockIdx.x * 256 + threadIdx.x;
  int d = idx & 31;
  int head = (idx >> 5) % (NH + NKV);
  int t = idx / ((NH + NKV) * 32);
  float pw = (float)d * (1.0f / 32.0f);
  float extrap = expf(-pw * 11.9183905733f);
  float interp = extrap * (1.0f / 32.0f);
  float ramp = fminf(fmaxf(((float)d - 8.0f) * 0.1f, 0.0f), 1.0f);
  float invf = interp * ramp + extrap * (1.0f - ramp);
  float fr = (float)positions[t] * invf;
  float s, c;
  sincosf(fr, &s, &c);
  c *= MSCALE;
  s *= MSCALE;
  if (head < NH) {
    const unsigned short* b = qkvb + (size_t)t * QKV_N + head * HD + d;
    float x1 = bf2f(b[0]), x2 = bf2f(b[32]);
    unsigned short* ob = qb + (size_t)t * ATT_N + head * HD + d;
    ob[0] = f2bf(x1 * c - x2 * s);
    ob[32] = f2bf(x2 * c + x1 * s);
  } else {
    int gk = head - NH;
    const unsigned short* b = qkvb + (size_t)t * QKV_N + NH * HD + gk * HD + d;
    float x1 = bf2f(b[0]), x2 = bf2f(b[32]);
    unsigned short* ob = kb + (size_t)t * (NKV * HD) + gk * HD + d;
    ob[0] = f2bf(x1 * c - x2 * s);
    ob[32] = f2bf(x2 * c + x1 * s);
  }
}

// ---------------- attention + uniformly-distributed w_o->bf16 conversion ----------------
__global__ __launch_bounds__(256) void attn_kernel(const unsigned short* __restrict__ qb,
                                                   const unsigned short* __restrict__ kb,
                                                   const unsigned short* __restrict__ vt,
                                                   const float* __restrict__ sinks,
                                                   unsigned short* __restrict__ att,
                                                   const float* __restrict__ wo_src,
                                                   unsigned short* __restrict__ wo_dst) {
  __shared__ unsigned short orep[4][16][72];
  {
    const int bid = blockIdx.y * gridDim.x + blockIdx.x;
    const int total = HID_D * 1024;
    for (int i = bid * 256 + threadIdx.x; i < total; i += 2048 * 256) {
      float4 v = ((const float4*)wo_src)[i];
      u16x4 o = { f2bf(v.x), f2bf(v.y), f2bf(v.z), f2bf(v.w) };
      ((u16x4*)wo_dst)[i] = o;
    }
  }
  const int lane = threadIdx.x & 63;
  const int wid = threadIdx.x >> 6;
  const int q0 = blockIdx.x * 16;
  const int h = blockIdx.y * 4 + wid;
  const int g = h >> 3;
  const int lq = lane & 15;
  const int ro = lane >> 4;

  bf16x8 bq0, bq1;
  {
    const unsigned short* qp = qb + (size_t)(q0 + lq) * ATT_N + h * HD + ro * 8;
    bq0 = *(const bf16x8*)qp;
    bq1 = *(const bf16x8*)(qp + 32);
  }
  float m_run = sinks[h];
  float l_run = 1.0f;
  f32x4 o0 = {0.f, 0.f, 0.f, 0.f}, o1 = o0, o2 = o0, o3 = o0;
  const int qg = q0 + lq;
  const int jstart = (q0 >= WIN) ? q0 - WIN : 0;

  for (int jt = jstart; jt <= q0; jt += 32) {
    f32x4 st0 = {0.f, 0.f, 0.f, 0.f}, st1 = st0;
    {
      int kr = jt + ((lq >> 2) << 3) + (lq & 3);
      int kr0 = min(kr, T_SEQ - 1);
      int kr1 = min(kr + 4, T_SEQ - 1);
      const unsigned short* kp0 = kb + (size_t)kr0 * (NKV * HD) + g * HD + ro * 8;
      const unsigned short* kp1 = kb + (size_t)kr1 * (NKV * HD) + g * HD + ro * 8;
      bf16x8 ka0a = *(const bf16x8*)kp0;
      bf16x8 ka0b = *(const bf16x8*)(kp0 + 32);
      bf16x8 ka1a = *(const bf16x8*)kp1;
      bf16x8 ka1b = *(const bf16x8*)(kp1 + 32);
      st0 = __builtin_amdgcn_mfma_f32_16x16x32_bf16(ka0a, bq0, st0, 0, 0, 0);
      st0 = __builtin_amdgcn_mfma_f32_16x16x32_bf16(ka0b, bq1, st0, 0, 0, 0);
      st1 = __builtin_amdgcn_mfma_f32_16x16x32_bf16(ka1a, bq0, st1, 0, 0, 0);
      st1 = __builtin_amdgcn_mfma_f32_16x16x32_bf16(ka1b, bq1, st1, 0, 0, 0);
    }
    float p[8];
    float tmax = -3.0e30f;
#pragma unroll
    for (int r = 0; r < 4; ++r) {
      int jg0 = jt + ro * 8 + r;
      int jg1 = jg0 + 4;
      float s0 = (jg0 <= qg && (qg - jg0) < WIN) ? st0[r] * RSCALE : -3.0e30f;
      float s1 = (jg1 <= qg && (qg - jg1) < WIN) ? st1[r] * RSCALE : -3.0e30f;
      p[r] = s0;
      p[r + 4] = s1;
      tmax = fmaxf(tmax, fmaxf(s0, s1));
    }
    tmax = fmaxf(tmax, __shfl_xor(tmax, 16));
    tmax = fmaxf(tmax, __shfl_xor(tmax, 32));
    float m_new = fmaxf(m_run, tmax);
    float rescale = expf(m_run - m_new);
    float psum = 0.f;
    bf16x8 pa;
#pragma unroll
    for (int jj = 0; jj < 8; ++jj) {
      float pe = expf(p[jj] - m_new);
      psum += pe;
      pa[jj] = (short)f2bf(pe);
    }
    psum += __shfl_xor(psum, 16);
    psum += __shfl_xor(psum, 32);
    l_run = l_run * rescale + psum;
    m_run = m_new;
    f32x4 rs4;
#pragma unroll
    for (int r = 0; r < 4; ++r) rs4[r] = __shfl(rescale, ro * 4 + r);
    o0 *= rs4; o1 *= rs4; o2 *= rs4; o3 *= rs4;
    int tb = jt + ro * 8;
    if (tb > T_SEQ - 8) tb = T_SEQ - 8;
    const unsigned short* vp = vt + (size_t)(g * HD + lq) * T_SEQ + tb;
    bf16x8 v0 = *(const bf16x8*)vp;
    bf16x8 v1 = *(const bf16x8*)(vp + 16 * T_SEQ);
    bf16x8 v2 = *(const bf16x8*)(vp + 32 * T_SEQ);
    bf16x8 v3 = *(const bf16x8*)(vp + 48 * T_SEQ);
    o0 = __builtin_amdgcn_mfma_f32_16x16x32_bf16(pa, v0, o0, 0, 0, 0);
    o1 = __builtin_amdgcn_mfma_f32_16x16x32_bf16(pa, v1, o1, 0, 0, 0);
    o2 = __builtin_amdgcn_mfma_f32_16x16x32_bf16(pa, v2, o2, 0, 0, 0);
    o3 = __builtin_amdgcn_mfma_f32_16x16x32_bf16(pa, v3, o3, 0, 0, 0);
  }

#pragma unroll
  for (int r = 0; r < 4; ++r) {
    float lr = __shfl(l_run, ro * 4 + r);
    float inv = 1.0f / lr;
    int row = ro * 4 + r;
    orep[wid][row][lq]      = f2bf(o0[r] * inv);
    orep[wid][row][lq + 16] = f2bf(o1[r] * inv);
    orep[wid][row][lq + 32] = f2bf(o2[r] * inv);
    orep[wid][row][lq + 48] = f2bf(o3[r] * inv);
  }
  {
    const int row = lane >> 2;
    const int seg = (lane & 3) << 4;
    u16x8 w0 = *(const u16x8*)&orep[wid][row][seg];
    u16x8 w1 = *(const u16x8*)&orep[wid][row][seg + 8];
    unsigned short* op = att + (size_t)(q0 + row) * ATT_N + h * HD + seg;
    *(u16x8*)op = w0;
    *(u16x8*)(op + 8) = w1;
  }
}

extern "C" void kernel_launch(void* const* d_in, const int* in_sizes, int n_in,
                              void* d_out, int out_size, void* d_ws, size_t ws_size,
                              hipStream_t stream) {
  const float* x = (const float*)d_in[0];
  const int* pos = (const int*)d_in[1];
  const float* norm_w = (const float*)d_in[2];
  const float* w_qkv = (const float*)d_in[3];
  const float* b_qkv = (const float*)d_in[4];
  const float* w_o = (const float*)d_in[5];
  const float* b_o = (const float*)d_in[6];
  const float* sinks = (const float*)d_in[7];
  float* out = (float*)d_out;

  unsigned short* t_bf = (unsigned short*)d_ws;                        // [2048][2944]
  unsigned short* wq_bf = t_bf + (size_t)T_SEQ * KPAD;                 // [5120][2944]
  unsigned short* wo_bf = wq_bf + (size_t)QKV_N * KPAD;                // [2880][4096] (region sized NOPAD)
  unsigned short* qkv_bf = wo_bf + (size_t)NOPAD * ATT_N;              // [2048][5120] bf16
  unsigned short* qb = qkv_bf + (size_t)T_SEQ * QKV_N;                 // [2048][4096]
  unsigned short* kb = qb + (size_t)T_SEQ * ATT_N;                     // [2048][512]
  unsigned short* vt = kb + (size_t)T_SEQ * NKV * HD;                  // [8][64][2048]
  unsigned short* att = vt + (size_t)NKV * HD * T_SEQ;                 // [2048][4096]

  // 1. RMSNorm + w_qkv conversion
  pre_kernel<<<3072, 256, 0, stream>>>(x, norm_w, t_bf, w_qkv, wq_bf);
  // 2. QKV GEMM: 128x320, 256 blocks (full chip)
  qkv320_kernel<<<256, 512, 0, stream>>>(t_bf, wq_bf, qkv_bf, b_qkv);
  // 3. RoPE (q,k) + V transpose, one launch
  ropevt_kernel<<<ROPE_BLKS + 256, 256, 0, stream>>>(qkv_bf, pos, qb, kb, vt);
  // 4. attention + distributed w_o conversion (must precede outproj)
  attn_kernel<<<dim3(T_SEQ / 16, NH / 4), 256, 0, stream>>>(qb, kb, vt, sinks, att, w_o, wo_bf);
  // 5. out projection: single-phase BK=64 2-buf 128x192 tiles, 240 blocks, 2 blocks/CU
  outproj192_kernel<<<240, 512, 0, stream>>>(att, wo_bf, out, b_o, x);
}

// Round 18
// 219.507 us; speedup vs baseline: 1.0748x; 1.0748x over previous
//
#include <hip/hip_runtime.h>
#include <hip/hip_bf16.h>
#include <stdint.h>

typedef __attribute__((ext_vector_type(8))) short bf16x8;
typedef __attribute__((ext_vector_type(8))) unsigned short u16x8;
typedef __attribute__((ext_vector_type(4))) float f32x4;
typedef __attribute__((ext_vector_type(4))) unsigned short u16x4;

#define T_SEQ 2048
#define HID_D 2880
#define KPAD 2944              // 2880 padded to 46*64
#define NH 64
#define NKV 8
#define HD 64
#define QKV_N 5120
#define ATT_N 4096
#define NOPAD 3072             // wo_bf region rows (layout constant)
#define WIN 128
#define RSCALE 0.125f
#define MSCALE 1.3465735903f
#define ROPE_TOT (T_SEQ * (NH + NKV) * 32)   // 4718592
#define ROPE_BLKS (ROPE_TOT / 256)           // 18432

__device__ __forceinline__ unsigned short f2bf(float f) {
  union { float f; unsigned u; } v; v.f = f;
  unsigned r = v.u + 0x7fffu + ((v.u >> 16) & 1u);
  return (unsigned short)(r >> 16);
}
__device__ __forceinline__ float bf2f(unsigned short u) {
  union { unsigned u; float f; } v; v.u = ((unsigned)u) << 16;
  return v.f;
}

__device__ __forceinline__ void gload_lds16(const void* g, void* l) {
  __builtin_amdgcn_global_load_lds((const __attribute__((address_space(1))) char*)g,
                                   (__attribute__((address_space(3))) char*)l, 16, 0, 0);
}

#define GPH_MID()                                        \
  __builtin_amdgcn_s_barrier();                          \
  asm volatile("s_waitcnt lgkmcnt(0)" ::: "memory");     \
  __builtin_amdgcn_sched_barrier(0);                     \
  __builtin_amdgcn_s_setprio(1)
#define GPH_END()                                        \
  __builtin_amdgcn_s_setprio(0);                         \
  __builtin_amdgcn_s_barrier()

// ---------------- fused RMSNorm (blocks 0..2047) + w_qkv->bf16 pad (blocks 2048..3071) ----------------
__global__ __launch_bounds__(256) void pre_kernel(const float* __restrict__ x,
                                                  const float* __restrict__ w,
                                                  unsigned short* __restrict__ t_bf,
                                                  const float* __restrict__ wq_src,
                                                  unsigned short* __restrict__ wq_dst) {
  __shared__ float red[256];
  if (blockIdx.x < 2048) {
    int row = blockIdx.x;
    const float4* xr4 = (const float4*)(x + (size_t)row * HID_D);
    const float4* w4 = (const float4*)w;
    float ss = 0.f;
    for (int i = threadIdx.x; i < 720; i += 256) {
      float4 v = xr4[i];
      ss += v.x * v.x + v.y * v.y + v.z * v.z + v.w * v.w;
    }
    red[threadIdx.x] = ss;
    __syncthreads();
    for (int s = 128; s > 0; s >>= 1) {
      if (threadIdx.x < s) red[threadIdx.x] += red[threadIdx.x + s];
      __syncthreads();
    }
    float rs = rsqrtf(red[0] / (float)HID_D + 1e-5f);
    u16x4* ob = (u16x4*)(t_bf + (size_t)row * KPAD);
    for (int i = threadIdx.x; i < 736; i += 256) {
      u16x4 o = {0, 0, 0, 0};
      if (i < 720) {
        float4 v = xr4[i];
        float4 g = w4[i];
        o = { f2bf(v.x * rs * g.x), f2bf(v.y * rs * g.y),
              f2bf(v.z * rs * g.z), f2bf(v.w * rs * g.w) };
      }
      ob[i] = o;
    }
  } else {
    const int total = QKV_N * 736;
    for (int i = (blockIdx.x - 2048) * 256 + threadIdx.x; i < total; i += 1024 * 256) {
      int c4 = i % 736, row = i / 736;
      u16x4 o = {0, 0, 0, 0};
      if (c4 < 720) {
        float4 v = ((const float4*)wq_src)[(size_t)row * 720 + c4];
        o = { f2bf(v.x), f2bf(v.y), f2bf(v.z), f2bf(v.w) };
      }
      ((u16x4*)wq_dst)[i] = o;
    }
  }
}

// ============ QKV GEMM: 128x320 tile, 256 blocks (16Mx16N), FULL K=2944 ============
__global__ __launch_bounds__(512, 2) void qkv320_kernel(const unsigned short* __restrict__ A,
                                                        const unsigned short* __restrict__ B,
                                                        unsigned short* __restrict__ C,
                                                        const float* __restrict__ bias) {
  __shared__ unsigned short sA[2 * 128 * 64];       // 32 KiB
  __shared__ unsigned short sB[3 * 320 * 64];       // 120 KiB

  const int tid = threadIdx.x;
  const int lane = tid & 63, wid = tid >> 6;
  const int wr = wid >> 2, wc = wid & 3;            // 2M x 4N waves: 64x80 each
  const int lq = lane & 15, ro = lane >> 4;

  const int c = blockIdx.x & 7, q = blockIdx.x >> 3;      // q: 0..31
  const int by = (c & 1) * 8 + (q & 7);
  const int bx = (c >> 1) * 4 + (q >> 3);
  const int m0 = by * 128, n0 = bx * 320;

  const int R0 = tid >> 3;
  const int g0 = (((tid & 7) ^ (R0 & 7)) << 3);
  const size_t aOff = (size_t)(m0 + R0) * KPAD + g0;
  size_t bOff[5];
#pragma unroll
  for (int r = 0; r < 5; ++r)
    bOff[r] = (size_t)(n0 + r * 64 + R0) * KPAD + g0;

  const int ck0 = ((ro ^ (lq & 7)) << 3);
  const int ck1 = (((4 + ro) ^ (lq & 7)) << 3);

#define QSTG_A(BUF, KT)                                                         \
  { unsigned short* _d = sA + (BUF) * 8192 + wid * 512;                         \
    const unsigned short* _s = A + aOff + (size_t)(KT) * 64;                    \
    gload_lds16(_s, _d); gload_lds16(_s + (size_t)64 * KPAD, _d + 4096); }
#define QSTG_B(BUF, KT)                                                         \
  { unsigned short* _d = sB + (BUF) * 20480 + wid * 512;                        \
    gload_lds16(B + bOff[0] + (KT) * 64, _d);                                   \
    gload_lds16(B + bOff[1] + (KT) * 64, _d + 4096);                            \
    gload_lds16(B + bOff[2] + (KT) * 64, _d + 8192);                            \
    gload_lds16(B + bOff[3] + (KT) * 64, _d + 12288);                           \
    gload_lds16(B + bOff[4] + (KT) * 64, _d + 16384); }

  bf16x8 aR[8];
  bf16x8 b00, b01, b10, b11, b20, b21, b30, b31, b40, b41;
  f32x4 acc[4][5] = {};

#define QLDA(BUF)                                                                          \
  { _Pragma("unroll") for (int ii = 0; ii < 4; ++ii) {                                     \
      const int _r = (BUF) * 8192 + (wr * 64 + ii * 16 + lq) * 64;                         \
      aR[ii * 2 + 0] = *(const bf16x8*)&sA[_r + ck0];                                      \
      aR[ii * 2 + 1] = *(const bf16x8*)&sA[_r + ck1]; } }
#define QLDB(BUF, J, D0, D1)                                                               \
  { const int _r = (BUF) * 20480 + (wc * 80 + (J) * 16 + lq) * 64;                         \
    D0 = *(const bf16x8*)&sB[_r + ck0];                                                    \
    D1 = *(const bf16x8*)&sB[_r + ck1]; }
#define QMM(J, B0, B1)                                                                     \
  { _Pragma("unroll") for (int ii = 0; ii < 4; ++ii) {                                     \
      acc[ii][J] = __builtin_amdgcn_mfma_f32_16x16x32_bf16(aR[ii * 2 + 0], B0, acc[ii][J], 0, 0, 0); \
      acc[ii][J] = __builtin_amdgcn_mfma_f32_16x16x32_bf16(aR[ii * 2 + 1], B1, acc[ii][J], 0, 0, 0); } }

  QSTG_B(0, 0); QSTG_A(0, 0);
  QSTG_B(1, 1); QSTG_A(1, 1);
  asm volatile("s_waitcnt vmcnt(7)" ::: "memory");
  __builtin_amdgcn_s_barrier();

  const int nt = 46;
  for (int T = 0; T < nt; ++T) {
    const bool more = (T + 2 < nt);
    const int bb = T % 3, bA = T & 1;
    QLDA(bA);
    QLDB(bb, 0, b00, b01);
    QLDB(bb, 1, b10, b11);
    if (more) QSTG_B((T + 2) % 3, T + 2);
    GPH_MID();
    QMM(0, b00, b01);
    QMM(1, b10, b11);
    GPH_END();
    QLDB(bb, 2, b20, b21);
    QLDB(bb, 3, b30, b31);
    QLDB(bb, 4, b40, b41);
    if (more) QSTG_A((T + 2) & 1, T + 2);
    GPH_MID();
    QMM(2, b20, b21);
    QMM(3, b30, b31);
    QMM(4, b40, b41);
    __builtin_amdgcn_s_setprio(0);
    if (more) asm volatile("s_waitcnt vmcnt(7)" ::: "memory");
    else      asm volatile("s_waitcnt vmcnt(0)" ::: "memory");
    __builtin_amdgcn_s_barrier();
  }
#undef QSTG_A
#undef QSTG_B
#undef QLDA
#undef QLDB
#undef QMM

#pragma unroll
  for (int ii = 0; ii < 4; ++ii) {
    const int gr = m0 + wr * 64 + ii * 16 + ro * 4;
#pragma unroll
    for (int j = 0; j < 5; ++j) {
      const int gc = n0 + wc * 80 + j * 16 + lq;
      const float bv = bias[gc];
#pragma unroll
      for (int r = 0; r < 4; ++r)
        C[(size_t)(gr + r) * QKV_N + gc] = f2bf(acc[ii][j][r] + bv);
    }
  }
}

// ============ out projection: 128x192 tile, FULL K=4096, 240 blocks, SINGLE-PHASE ============
// A 3-buf (48KB) + B 3-buf (72KB) = 120 KB. One barrier pair per K-tile; depth-2
// prefetch with counted vmcnt(5) (never drains to 0 mid-loop). Round-15 proven form.
__global__ __launch_bounds__(512, 2) void outproj192_kernel(const unsigned short* __restrict__ att,
                                                            const unsigned short* __restrict__ wo,
                                                            float* __restrict__ out,
                                                            const float* __restrict__ b_o,
                                                            const float* __restrict__ x) {
  __shared__ unsigned short sA[3 * 128 * 64];       // 48 KiB
  __shared__ unsigned short sB[3 * 192 * 64];       // 72 KiB

  const int tid = threadIdx.x;
  const int lane = tid & 63, wid = tid >> 6;
  const int wr = wid >> 2, wc = wid & 3;            // 2M x 4N waves: 64x48 each
  const int lq = lane & 15, ro = lane >> 4;

  const int c = blockIdx.x & 7, q = blockIdx.x >> 3;      // q: 0..29
  const int by = c * 2 + (q >= 15 ? 1 : 0);
  const int bx = (q >= 15) ? q - 15 : q;
  const int m0 = by * 128, n0 = bx * 192;

  const int R0 = tid >> 3;
  const int g0 = (((tid & 7) ^ (R0 & 7)) << 3);
  const size_t aOff = (size_t)(m0 + R0) * ATT_N + g0;
  size_t bOff[3];
#pragma unroll
  for (int r = 0; r < 3; ++r)
    bOff[r] = (size_t)(n0 + r * 64 + R0) * ATT_N + g0;

  const int ck0 = ((ro ^ (lq & 7)) << 3);
  const int ck1 = (((4 + ro) ^ (lq & 7)) << 3);

#define PSTG_A(BUF, KT)                                                         \
  { unsigned short* _d = sA + (BUF) * 8192 + wid * 512;                         \
    const unsigned short* _s = att + aOff + (size_t)(KT) * 64;                  \
    gload_lds16(_s, _d); gload_lds16(_s + (size_t)64 * ATT_N, _d + 4096); }
#define PSTG_B(BUF, KT)                                                         \
  { unsigned short* _d = sB + (BUF) * 12288 + wid * 512;                        \
    gload_lds16(wo + bOff[0] + (KT) * 64, _d);                                  \
    gload_lds16(wo + bOff[1] + (KT) * 64, _d + 4096);                           \
    gload_lds16(wo + bOff[2] + (KT) * 64, _d + 8192); }

  bf16x8 aR[8];
  bf16x8 b00, b01, b10, b11, b20, b21;
  f32x4 acc[4][3] = {};

#define PLDA(BUF)                                                                          \
  { _Pragma("unroll") for (int ii = 0; ii < 4; ++ii) {                                     \
      const int _r = (BUF) * 8192 + (wr * 64 + ii * 16 + lq) * 64;                         \
      aR[ii * 2 + 0] = *(const bf16x8*)&sA[_r + ck0];                                      \
      aR[ii * 2 + 1] = *(const bf16x8*)&sA[_r + ck1]; } }
#define PLDB(BUF, J, D0, D1)                                                               \
  { const int _r = (BUF) * 12288 + (wc * 48 + (J) * 16 + lq) * 64;                         \
    D0 = *(const bf16x8*)&sB[_r + ck0];                                                    \
    D1 = *(const bf16x8*)&sB[_r + ck1]; }

  // prologue: tiles 0 (buf0) and 1 (buf1)
  PSTG_B(0, 0); PSTG_A(0, 0);
  PSTG_B(1, 1); PSTG_A(1, 1);
  asm volatile("s_waitcnt vmcnt(5)" ::: "memory");
  __builtin_amdgcn_s_barrier();

  const int nt = 64;
  for (int T = 0; T < nt; ++T) {
    const bool more = (T + 2 < nt);
    const int bb = T % 3;
    // issue all reads of tile T and all stages of tile T+2
    PLDA(bb);
    PLDB(bb, 0, b00, b01);
    PLDB(bb, 1, b10, b11);
    PLDB(bb, 2, b20, b21);
    if (more) { PSTG_B((T + 2) % 3, T + 2); PSTG_A((T + 2) % 3, T + 2); }
    GPH_MID();
#pragma unroll
    for (int ii = 0; ii < 4; ++ii) {
      acc[ii][0] = __builtin_amdgcn_mfma_f32_16x16x32_bf16(aR[ii * 2 + 0], b00, acc[ii][0], 0, 0, 0);
      acc[ii][0] = __builtin_amdgcn_mfma_f32_16x16x32_bf16(aR[ii * 2 + 1], b01, acc[ii][0], 0, 0, 0);
      acc[ii][1] = __builtin_amdgcn_mfma_f32_16x16x32_bf16(aR[ii * 2 + 0], b10, acc[ii][1], 0, 0, 0);
      acc[ii][1] = __builtin_amdgcn_mfma_f32_16x16x32_bf16(aR[ii * 2 + 1], b11, acc[ii][1], 0, 0, 0);
      acc[ii][2] = __builtin_amdgcn_mfma_f32_16x16x32_bf16(aR[ii * 2 + 0], b20, acc[ii][2], 0, 0, 0);
      acc[ii][2] = __builtin_amdgcn_mfma_f32_16x16x32_bf16(aR[ii * 2 + 1], b21, acc[ii][2], 0, 0, 0);
    }
    __builtin_amdgcn_s_setprio(0);
    if (more) asm volatile("s_waitcnt vmcnt(5)" ::: "memory");
    else      asm volatile("s_waitcnt vmcnt(0)" ::: "memory");
    __builtin_amdgcn_s_barrier();
  }
#undef PSTG_A
#undef PSTG_B
#undef PLDA
#undef PLDB

#pragma unroll
  for (int ii = 0; ii < 4; ++ii) {
    const int gr = m0 + wr * 64 + ii * 16 + ro * 4;
#pragma unroll
    for (int j = 0; j < 3; ++j) {
      const int gc = n0 + wc * 48 + j * 16 + lq;
      const float bv = b_o[gc];
#pragma unroll
      for (int r = 0; r < 4; ++r) {
        size_t off = (size_t)(gr + r) * HID_D + gc;
        out[off] = acc[ii][j][r] + bv + x[off];
      }
    }
  }
}

// ---------------- fused YaRN RoPE (blocks 0..18431) + V transpose (blocks 18432..18687) ----------------
__global__ __launch_bounds__(256) void ropevt_kernel(const unsigned short* __restrict__ qkvb,
                                                     const int* __restrict__ positions,
                                                     unsigned short* __restrict__ qb,
                                                     unsigned short* __restrict__ kb,
                                                     unsigned short* __restrict__ vt) {
  __shared__ unsigned short tile[64][72];
  if (blockIdx.x >= ROPE_BLKS) {
    const int vb = blockIdx.x - ROPE_BLKS;
    const int g = vb >> 5;
    const int t0 = (vb & 31) << 6;
    const int r = threadIdx.x >> 3;
    const int c8 = (threadIdx.x & 7) << 3;
    const size_t vbase = (size_t)(NH + NKV) * HD + (size_t)g * HD;
#pragma unroll
    for (int hh = 0; hh < 2; ++hh) {
      int row = r + hh * 32;
      *(u16x8*)&tile[row][c8] =
          *(const u16x8*)(qkvb + (size_t)(t0 + row) * QKV_N + vbase + c8);
    }
    __syncthreads();
    const int d = threadIdx.x >> 2;
    const int ts = (threadIdx.x & 3) << 4;
    u16x8 v0, v1;
#pragma unroll
    for (int i = 0; i < 8; ++i) { v0[i] = tile[ts + i][d]; v1[i] = tile[ts + 8 + i][d]; }
    unsigned short* dst = vt + (size_t)(g * HD + d) * T_SEQ + t0 + ts;
    *(u16x8*)dst = v0;
    *(u16x8*)(dst + 8) = v1;
    return;
  }
  int idx = blockIdx.x * 256 + threadIdx.x;
  int d = idx & 31;
  int head = (idx >> 5) % (NH + NKV);
  int t = idx / ((NH + NKV) * 32);
  float pw = (float)d * (1.0f / 32.0f);
  float extrap = expf(-pw * 11.9183905733f);
  float interp = extrap * (1.0f / 32.0f);
  float ramp = fminf(fmaxf(((float)d - 8.0f) * 0.1f, 0.0f), 1.0f);
  float invf = interp * ramp + extrap * (1.0f - ramp);
  float fr = (float)positions[t] * invf;
  float s, c;
  sincosf(fr, &s, &c);
  c *= MSCALE;
  s *= MSCALE;
  if (head < NH) {
    const unsigned short* b = qkvb + (size_t)t * QKV_N + head * HD + d;
    float x1 = bf2f(b[0]), x2 = bf2f(b[32]);
    unsigned short* ob = qb + (size_t)t * ATT_N + head * HD + d;
    ob[0] = f2bf(x1 * c - x2 * s);
    ob[32] = f2bf(x2 * c + x1 * s);
  } else {
    int gk = head - NH;
    const unsigned short* b = qkvb + (size_t)t * QKV_N + NH * HD + gk * HD + d;
    float x1 = bf2f(b[0]), x2 = bf2f(b[32]);
    unsigned short* ob = kb + (size_t)t * (NKV * HD) + gk * HD + d;
    ob[0] = f2bf(x1 * c - x2 * s);
    ob[32] = f2bf(x2 * c + x1 * s);
  }
}

// ---------------- attention + uniformly-distributed w_o->bf16 conversion ----------------
__global__ __launch_bounds__(256) void attn_kernel(const unsigned short* __restrict__ qb,
                                                   const unsigned short* __restrict__ kb,
                                                   const unsigned short* __restrict__ vt,
                                                   const float* __restrict__ sinks,
                                                   unsigned short* __restrict__ att,
                                                   const float* __restrict__ wo_src,
                                                   unsigned short* __restrict__ wo_dst) {
  __shared__ unsigned short orep[4][16][72];
  {
    const int bid = blockIdx.y * gridDim.x + blockIdx.x;
    const int total = HID_D * 1024;
    for (int i = bid * 256 + threadIdx.x; i < total; i += 2048 * 256) {
      float4 v = ((const float4*)wo_src)[i];
      u16x4 o = { f2bf(v.x), f2bf(v.y), f2bf(v.z), f2bf(v.w) };
      ((u16x4*)wo_dst)[i] = o;
    }
  }
  const int lane = threadIdx.x & 63;
  const int wid = threadIdx.x >> 6;
  const int q0 = blockIdx.x * 16;
  const int h = blockIdx.y * 4 + wid;
  const int g = h >> 3;
  const int lq = lane & 15;
  const int ro = lane >> 4;

  bf16x8 bq0, bq1;
  {
    const unsigned short* qp = qb + (size_t)(q0 + lq) * ATT_N + h * HD + ro * 8;
    bq0 = *(const bf16x8*)qp;
    bq1 = *(const bf16x8*)(qp + 32);
  }
  float m_run = sinks[h];
  float l_run = 1.0f;
  f32x4 o0 = {0.f, 0.f, 0.f, 0.f}, o1 = o0, o2 = o0, o3 = o0;
  const int qg = q0 + lq;
  const int jstart = (q0 >= WIN) ? q0 - WIN : 0;

  for (int jt = jstart; jt <= q0; jt += 32) {
    f32x4 st0 = {0.f, 0.f, 0.f, 0.f}, st1 = st0;
    {
      int kr = jt + ((lq >> 2) << 3) + (lq & 3);
      int kr0 = min(kr, T_SEQ - 1);
      int kr1 = min(kr + 4, T_SEQ - 1);
      const unsigned short* kp0 = kb + (size_t)kr0 * (NKV * HD) + g * HD + ro * 8;
      const unsigned short* kp1 = kb + (size_t)kr1 * (NKV * HD) + g * HD + ro * 8;
      bf16x8 ka0a = *(const bf16x8*)kp0;
      bf16x8 ka0b = *(const bf16x8*)(kp0 + 32);
      bf16x8 ka1a = *(const bf16x8*)kp1;
      bf16x8 ka1b = *(const bf16x8*)(kp1 + 32);
      st0 = __builtin_amdgcn_mfma_f32_16x16x32_bf16(ka0a, bq0, st0, 0, 0, 0);
      st0 = __builtin_amdgcn_mfma_f32_16x16x32_bf16(ka0b, bq1, st0, 0, 0, 0);
      st1 = __builtin_amdgcn_mfma_f32_16x16x32_bf16(ka1a, bq0, st1, 0, 0, 0);
      st1 = __builtin_amdgcn_mfma_f32_16x16x32_bf16(ka1b, bq1, st1, 0, 0, 0);
    }
    float p[8];
    float tmax = -3.0e30f;
#pragma unroll
    for (int r = 0; r < 4; ++r) {
      int jg0 = jt + ro * 8 + r;
      int jg1 = jg0 + 4;
      float s0 = (jg0 <= qg && (qg - jg0) < WIN) ? st0[r] * RSCALE : -3.0e30f;
      float s1 = (jg1 <= qg && (qg - jg1) < WIN) ? st1[r] * RSCALE : -3.0e30f;
      p[r] = s0;
      p[r + 4] = s1;
      tmax = fmaxf(tmax, fmaxf(s0, s1));
    }
    tmax = fmaxf(tmax, __shfl_xor(tmax, 16));
    tmax = fmaxf(tmax, __shfl_xor(tmax, 32));
    float m_new = fmaxf(m_run, tmax);
    float rescale = expf(m_run - m_new);
    float psum = 0.f;
    bf16x8 pa;
#pragma unroll
    for (int jj = 0; jj < 8; ++jj) {
      float pe = expf(p[jj] - m_new);
      psum += pe;
      pa[jj] = (short)f2bf(pe);
    }
    psum += __shfl_xor(psum, 16);
    psum += __shfl_xor(psum, 32);
    l_run = l_run * rescale + psum;
    m_run = m_new;
    f32x4 rs4;
#pragma unroll
    for (int r = 0; r < 4; ++r) rs4[r] = __shfl(rescale, ro * 4 + r);
    o0 *= rs4; o1 *= rs4; o2 *= rs4; o3 *= rs4;
    int tb = jt + ro * 8;
    if (tb > T_SEQ - 8) tb = T_SEQ - 8;
    const unsigned short* vp = vt + (size_t)(g * HD + lq) * T_SEQ + tb;
    bf16x8 v0 = *(const bf16x8*)vp;
    bf16x8 v1 = *(const bf16x8*)(vp + 16 * T_SEQ);
    bf16x8 v2 = *(const bf16x8*)(vp + 32 * T_SEQ);
    bf16x8 v3 = *(const bf16x8*)(vp + 48 * T_SEQ);
    o0 = __builtin_amdgcn_mfma_f32_16x16x32_bf16(pa, v0, o0, 0, 0, 0);
    o1 = __builtin_amdgcn_mfma_f32_16x16x32_bf16(pa, v1, o1, 0, 0, 0);
    o2 = __builtin_amdgcn_mfma_f32_16x16x32_bf16(pa, v2, o2, 0, 0, 0);
    o3 = __builtin_amdgcn_mfma_f32_16x16x32_bf16(pa, v3, o3, 0, 0, 0);
  }

#pragma unroll
  for (int r = 0; r < 4; ++r) {
    float lr = __shfl(l_run, ro * 4 + r);
    float inv = 1.0f / lr;
    int row = ro * 4 + r;
    orep[wid][row][lq]      = f2bf(o0[r] * inv);
    orep[wid][row][lq + 16] = f2bf(o1[r] * inv);
    orep[wid][row][lq + 32] = f2bf(o2[r] * inv);
    orep[wid][row][lq + 48] = f2bf(o3[r] * inv);
  }
  {
    const int row = lane >> 2;
    const int seg = (lane & 3) << 4;
    u16x8 w0 = *(const u16x8*)&orep[wid][row][seg];
    u16x8 w1 = *(const u16x8*)&orep[wid][row][seg + 8];
    unsigned short* op = att + (size_t)(q0 + row) * ATT_N + h * HD + seg;
    *(u16x8*)op = w0;
    *(u16x8*)(op + 8) = w1;
  }
}

extern "C" void kernel_launch(void* const* d_in, const int* in_sizes, int n_in,
                              void* d_out, int out_size, void* d_ws, size_t ws_size,
                              hipStream_t stream) {
  const float* x = (const float*)d_in[0];
  const int* pos = (const int*)d_in[1];
  const float* norm_w = (const float*)d_in[2];
  const float* w_qkv = (const float*)d_in[3];
  const float* b_qkv = (const float*)d_in[4];
  const float* w_o = (const float*)d_in[5];
  const float* b_o = (const float*)d_in[6];
  const float* sinks = (const float*)d_in[7];
  float* out = (float*)d_out;

  unsigned short* t_bf = (unsigned short*)d_ws;                        // [2048][2944]
  unsigned short* wq_bf = t_bf + (size_t)T_SEQ * KPAD;                 // [5120][2944]
  unsigned short* wo_bf = wq_bf + (size_t)QKV_N * KPAD;                // [2880][4096] (region sized NOPAD)
  unsigned short* qkv_bf = wo_bf + (size_t)NOPAD * ATT_N;              // [2048][5120] bf16
  unsigned short* qb = qkv_bf + (size_t)T_SEQ * QKV_N;                 // [2048][4096]
  unsigned short* kb = qb + (size_t)T_SEQ * ATT_N;                     // [2048][512]
  unsigned short* vt = kb + (size_t)T_SEQ * NKV * HD;                  // [8][64][2048]
  unsigned short* att = vt + (size_t)NKV * HD * T_SEQ;                 // [2048][4096]

  // 1. RMSNorm + w_qkv conversion
  pre_kernel<<<3072, 256, 0, stream>>>(x, norm_w, t_bf, w_qkv, wq_bf);
  // 2. QKV GEMM: 128x320, 256 blocks (full chip)
  qkv320_kernel<<<256, 512, 0, stream>>>(t_bf, wq_bf, qkv_bf, b_qkv);
  // 3. RoPE (q,k) + V transpose, one launch
  ropevt_kernel<<<ROPE_BLKS + 256, 256, 0, stream>>>(qkv_bf, pos, qb, kb, vt);
  // 4. attention + distributed w_o conversion (must precede outproj)
  attn_kernel<<<dim3(T_SEQ / 16, NH / 4), 256, 0, stream>>>(qb, kb, vt, sinks, att, w_o, wo_bf);
  // 5. out projection: single-phase 3-buf 128x192 tiles, counted vmcnt(5), 240 blocks
  outproj192_kernel<<<240, 512, 0, stream>>>(att, wo_bf, out, b_o, x);
}

// Round 19
// 218.286 us; speedup vs baseline: 1.0808x; 1.0056x over previous
//
#include <hip/hip_runtime.h>
#include <hip/hip_bf16.h>
#include <stdint.h>

typedef __attribute__((ext_vector_type(8))) short bf16x8;
typedef __attribute__((ext_vector_type(8))) unsigned short u16x8;
typedef __attribute__((ext_vector_type(4))) float f32x4;
typedef __attribute__((ext_vector_type(4))) unsigned short u16x4;

#define T_SEQ 2048
#define HID_D 2880
#define KPAD 2944              // 2880 padded to 46*64
#define NH 64
#define NKV 8
#define HD 64
#define QKV_N 5120
#define ATT_N 4096
#define NOPAD 3072             // wo_bf region rows (layout constant)
#define WIN 128
#define RSCALE 0.125f
#define MSCALE 1.3465735903f
#define ROPE_TOT (T_SEQ * (NH + NKV) * 32)   // 4718592
#define ROPE_BLKS (ROPE_TOT / 256)           // 18432

__device__ __forceinline__ unsigned short f2bf(float f) {
  union { float f; unsigned u; } v; v.f = f;
  unsigned r = v.u + 0x7fffu + ((v.u >> 16) & 1u);
  return (unsigned short)(r >> 16);
}
__device__ __forceinline__ float bf2f(unsigned short u) {
  union { unsigned u; float f; } v; v.u = ((unsigned)u) << 16;
  return v.f;
}

__device__ __forceinline__ void gload_lds16(const void* g, void* l) {
  __builtin_amdgcn_global_load_lds((const __attribute__((address_space(1))) char*)g,
                                   (__attribute__((address_space(3))) char*)l, 16, 0, 0);
}

// Phase-enter: barrier + setprio only. ds_reads are same-phase plain loads, so the
// compiler inserts fine-grained lgkmcnt itself (m97); an explicit lgkmcnt(0)+
// sched_barrier(0) here would force a full serial drain (m141 anti-pattern).
#define GPH_MID()                                        \
  __builtin_amdgcn_s_barrier();                          \
  __builtin_amdgcn_s_setprio(1)
#define GPH_END()                                        \
  __builtin_amdgcn_s_setprio(0);                         \
  __builtin_amdgcn_s_barrier()

// ---------------- fused RMSNorm (blocks 0..2047) + w_qkv->bf16 pad (blocks 2048..3071) ----------------
__global__ __launch_bounds__(256) void pre_kernel(const float* __restrict__ x,
                                                  const float* __restrict__ w,
                                                  unsigned short* __restrict__ t_bf,
                                                  const float* __restrict__ wq_src,
                                                  unsigned short* __restrict__ wq_dst) {
  __shared__ float red[256];
  if (blockIdx.x < 2048) {
    int row = blockIdx.x;
    const float4* xr4 = (const float4*)(x + (size_t)row * HID_D);
    const float4* w4 = (const float4*)w;
    float ss = 0.f;
    for (int i = threadIdx.x; i < 720; i += 256) {
      float4 v = xr4[i];
      ss += v.x * v.x + v.y * v.y + v.z * v.z + v.w * v.w;
    }
    red[threadIdx.x] = ss;
    __syncthreads();
    for (int s = 128; s > 0; s >>= 1) {
      if (threadIdx.x < s) red[threadIdx.x] += red[threadIdx.x + s];
      __syncthreads();
    }
    float rs = rsqrtf(red[0] / (float)HID_D + 1e-5f);
    u16x4* ob = (u16x4*)(t_bf + (size_t)row * KPAD);
    for (int i = threadIdx.x; i < 736; i += 256) {
      u16x4 o = {0, 0, 0, 0};
      if (i < 720) {
        float4 v = xr4[i];
        float4 g = w4[i];
        o = { f2bf(v.x * rs * g.x), f2bf(v.y * rs * g.y),
              f2bf(v.z * rs * g.z), f2bf(v.w * rs * g.w) };
      }
      ob[i] = o;
    }
  } else {
    const int total = QKV_N * 736;
    for (int i = (blockIdx.x - 2048) * 256 + threadIdx.x; i < total; i += 1024 * 256) {
      int c4 = i % 736, row = i / 736;
      u16x4 o = {0, 0, 0, 0};
      if (c4 < 720) {
        float4 v = ((const float4*)wq_src)[(size_t)row * 720 + c4];
        o = { f2bf(v.x), f2bf(v.y), f2bf(v.z), f2bf(v.w) };
      }
      ((u16x4*)wq_dst)[i] = o;
    }
  }
}

// ============ QKV GEMM: 128x320 tile, 256 blocks (16Mx16N), FULL K=2944 ============
__global__ __launch_bounds__(512, 2) void qkv320_kernel(const unsigned short* __restrict__ A,
                                                        const unsigned short* __restrict__ B,
                                                        unsigned short* __restrict__ C,
                                                        const float* __restrict__ bias) {
  __shared__ unsigned short sA[2 * 128 * 64];       // 32 KiB
  __shared__ unsigned short sB[3 * 320 * 64];       // 120 KiB

  const int tid = threadIdx.x;
  const int lane = tid & 63, wid = tid >> 6;
  const int wr = wid >> 2, wc = wid & 3;            // 2M x 4N waves: 64x80 each
  const int lq = lane & 15, ro = lane >> 4;

  const int c = blockIdx.x & 7, q = blockIdx.x >> 3;      // q: 0..31
  const int by = (c & 1) * 8 + (q & 7);
  const int bx = (c >> 1) * 4 + (q >> 3);
  const int m0 = by * 128, n0 = bx * 320;

  const int R0 = tid >> 3;
  const int g0 = (((tid & 7) ^ (R0 & 7)) << 3);
  const size_t aOff = (size_t)(m0 + R0) * KPAD + g0;
  size_t bOff[5];
#pragma unroll
  for (int r = 0; r < 5; ++r)
    bOff[r] = (size_t)(n0 + r * 64 + R0) * KPAD + g0;

  const int ck0 = ((ro ^ (lq & 7)) << 3);
  const int ck1 = (((4 + ro) ^ (lq & 7)) << 3);

#define QSTG_A(BUF, KT)                                                         \
  { unsigned short* _d = sA + (BUF) * 8192 + wid * 512;                         \
    const unsigned short* _s = A + aOff + (size_t)(KT) * 64;                    \
    gload_lds16(_s, _d); gload_lds16(_s + (size_t)64 * KPAD, _d + 4096); }
#define QSTG_B(BUF, KT)                                                         \
  { unsigned short* _d = sB + (BUF) * 20480 + wid * 512;                        \
    gload_lds16(B + bOff[0] + (KT) * 64, _d);                                   \
    gload_lds16(B + bOff[1] + (KT) * 64, _d + 4096);                            \
    gload_lds16(B + bOff[2] + (KT) * 64, _d + 8192);                            \
    gload_lds16(B + bOff[3] + (KT) * 64, _d + 12288);                           \
    gload_lds16(B + bOff[4] + (KT) * 64, _d + 16384); }

  bf16x8 aR[8];
  bf16x8 b00, b01, b10, b11, b20, b21, b30, b31, b40, b41;
  f32x4 acc[4][5] = {};

#define QLDA(BUF)                                                                          \
  { _Pragma("unroll") for (int ii = 0; ii < 4; ++ii) {                                     \
      const int _r = (BUF) * 8192 + (wr * 64 + ii * 16 + lq) * 64;                         \
      aR[ii * 2 + 0] = *(const bf16x8*)&sA[_r + ck0];                                      \
      aR[ii * 2 + 1] = *(const bf16x8*)&sA[_r + ck1]; } }
#define QLDB(BUF, J, D0, D1)                                                               \
  { const int _r = (BUF) * 20480 + (wc * 80 + (J) * 16 + lq) * 64;                         \
    D0 = *(const bf16x8*)&sB[_r + ck0];                                                    \
    D1 = *(const bf16x8*)&sB[_r + ck1]; }
#define QMM(J, B0, B1)                                                                     \
  { _Pragma("unroll") for (int ii = 0; ii < 4; ++ii) {                                     \
      acc[ii][J] = __builtin_amdgcn_mfma_f32_16x16x32_bf16(aR[ii * 2 + 0], B0, acc[ii][J], 0, 0, 0); \
      acc[ii][J] = __builtin_amdgcn_mfma_f32_16x16x32_bf16(aR[ii * 2 + 1], B1, acc[ii][J], 0, 0, 0); } }

  QSTG_B(0, 0); QSTG_A(0, 0);
  QSTG_B(1, 1); QSTG_A(1, 1);
  asm volatile("s_waitcnt vmcnt(7)" ::: "memory");
  __builtin_amdgcn_s_barrier();

  const int nt = 46;
  for (int T = 0; T < nt; ++T) {
    const bool more = (T + 2 < nt);
    const int bb = T % 3, bA = T & 1;
    QLDA(bA);
    QLDB(bb, 0, b00, b01);
    QLDB(bb, 1, b10, b11);
    if (more) QSTG_B((T + 2) % 3, T + 2);
    GPH_MID();
    QMM(0, b00, b01);
    QMM(1, b10, b11);
    GPH_END();
    QLDB(bb, 2, b20, b21);
    QLDB(bb, 3, b30, b31);
    QLDB(bb, 4, b40, b41);
    if (more) QSTG_A((T + 2) & 1, T + 2);
    GPH_MID();
    QMM(2, b20, b21);
    QMM(3, b30, b31);
    QMM(4, b40, b41);
    __builtin_amdgcn_s_setprio(0);
    if (more) asm volatile("s_waitcnt vmcnt(7)" ::: "memory");
    else      asm volatile("s_waitcnt vmcnt(0)" ::: "memory");
    __builtin_amdgcn_s_barrier();
  }
#undef QSTG_A
#undef QSTG_B
#undef QLDA
#undef QLDB
#undef QMM

#pragma unroll
  for (int ii = 0; ii < 4; ++ii) {
    const int gr = m0 + wr * 64 + ii * 16 + ro * 4;
#pragma unroll
    for (int j = 0; j < 5; ++j) {
      const int gc = n0 + wc * 80 + j * 16 + lq;
      const float bv = bias[gc];
#pragma unroll
      for (int r = 0; r < 4; ++r)
        C[(size_t)(gr + r) * QKV_N + gc] = f2bf(acc[ii][j][r] + bv);
    }
  }
}

// ============ out projection: 128x192 tile, FULL K=4096, 240 blocks, SINGLE-PHASE ============
// A 3-buf (48KB) + B 3-buf (72KB) = 120 KB. One barrier pair per K-tile; depth-2
// prefetch with counted vmcnt(5) (never drains to 0 mid-loop).
__global__ __launch_bounds__(512, 2) void outproj192_kernel(const unsigned short* __restrict__ att,
                                                            const unsigned short* __restrict__ wo,
                                                            float* __restrict__ out,
                                                            const float* __restrict__ b_o,
                                                            const float* __restrict__ x) {
  __shared__ unsigned short sA[3 * 128 * 64];       // 48 KiB
  __shared__ unsigned short sB[3 * 192 * 64];       // 72 KiB

  const int tid = threadIdx.x;
  const int lane = tid & 63, wid = tid >> 6;
  const int wr = wid >> 2, wc = wid & 3;            // 2M x 4N waves: 64x48 each
  const int lq = lane & 15, ro = lane >> 4;

  const int c = blockIdx.x & 7, q = blockIdx.x >> 3;      // q: 0..29
  const int by = c * 2 + (q >= 15 ? 1 : 0);
  const int bx = (q >= 15) ? q - 15 : q;
  const int m0 = by * 128, n0 = bx * 192;

  const int R0 = tid >> 3;
  const int g0 = (((tid & 7) ^ (R0 & 7)) << 3);
  const size_t aOff = (size_t)(m0 + R0) * ATT_N + g0;
  size_t bOff[3];
#pragma unroll
  for (int r = 0; r < 3; ++r)
    bOff[r] = (size_t)(n0 + r * 64 + R0) * ATT_N + g0;

  const int ck0 = ((ro ^ (lq & 7)) << 3);
  const int ck1 = (((4 + ro) ^ (lq & 7)) << 3);

#define PSTG_A(BUF, KT)                                                         \
  { unsigned short* _d = sA + (BUF) * 8192 + wid * 512;                         \
    const unsigned short* _s = att + aOff + (size_t)(KT) * 64;                  \
    gload_lds16(_s, _d); gload_lds16(_s + (size_t)64 * ATT_N, _d + 4096); }
#define PSTG_B(BUF, KT)                                                         \
  { unsigned short* _d = sB + (BUF) * 12288 + wid * 512;                        \
    gload_lds16(wo + bOff[0] + (KT) * 64, _d);                                  \
    gload_lds16(wo + bOff[1] + (KT) * 64, _d + 4096);                           \
    gload_lds16(wo + bOff[2] + (KT) * 64, _d + 8192); }

  bf16x8 aR[8];
  bf16x8 b00, b01, b10, b11, b20, b21;
  f32x4 acc[4][3] = {};

#define PLDA(BUF)                                                                          \
  { _Pragma("unroll") for (int ii = 0; ii < 4; ++ii) {                                     \
      const int _r = (BUF) * 8192 + (wr * 64 + ii * 16 + lq) * 64;                         \
      aR[ii * 2 + 0] = *(const bf16x8*)&sA[_r + ck0];                                      \
      aR[ii * 2 + 1] = *(const bf16x8*)&sA[_r + ck1]; } }
#define PLDB(BUF, J, D0, D1)                                                               \
  { const int _r = (BUF) * 12288 + (wc * 48 + (J) * 16 + lq) * 64;                         \
    D0 = *(const bf16x8*)&sB[_r + ck0];                                                    \
    D1 = *(const bf16x8*)&sB[_r + ck1]; }

  // prologue: tiles 0 (buf0) and 1 (buf1)
  PSTG_B(0, 0); PSTG_A(0, 0);
  PSTG_B(1, 1); PSTG_A(1, 1);
  asm volatile("s_waitcnt vmcnt(5)" ::: "memory");
  __builtin_amdgcn_s_barrier();

  const int nt = 64;
  for (int T = 0; T < nt; ++T) {
    const bool more = (T + 2 < nt);
    const int bb = T % 3;
    // issue all reads of tile T and all stages of tile T+2
    PLDA(bb);
    PLDB(bb, 0, b00, b01);
    PLDB(bb, 1, b10, b11);
    PLDB(bb, 2, b20, b21);
    if (more) { PSTG_B((T + 2) % 3, T + 2); PSTG_A((T + 2) % 3, T + 2); }
    GPH_MID();
#pragma unroll
    for (int ii = 0; ii < 4; ++ii) {
      acc[ii][0] = __builtin_amdgcn_mfma_f32_16x16x32_bf16(aR[ii * 2 + 0], b00, acc[ii][0], 0, 0, 0);
      acc[ii][0] = __builtin_amdgcn_mfma_f32_16x16x32_bf16(aR[ii * 2 + 1], b01, acc[ii][0], 0, 0, 0);
      acc[ii][1] = __builtin_amdgcn_mfma_f32_16x16x32_bf16(aR[ii * 2 + 0], b10, acc[ii][1], 0, 0, 0);
      acc[ii][1] = __builtin_amdgcn_mfma_f32_16x16x32_bf16(aR[ii * 2 + 1], b11, acc[ii][1], 0, 0, 0);
      acc[ii][2] = __builtin_amdgcn_mfma_f32_16x16x32_bf16(aR[ii * 2 + 0], b20, acc[ii][2], 0, 0, 0);
      acc[ii][2] = __builtin_amdgcn_mfma_f32_16x16x32_bf16(aR[ii * 2 + 1], b21, acc[ii][2], 0, 0, 0);
    }
    __builtin_amdgcn_s_setprio(0);
    if (more) asm volatile("s_waitcnt vmcnt(5)" ::: "memory");
    else      asm volatile("s_waitcnt vmcnt(0)" ::: "memory");
    __builtin_amdgcn_s_barrier();
  }
#undef PSTG_A
#undef PSTG_B
#undef PLDA
#undef PLDB

#pragma unroll
  for (int ii = 0; ii < 4; ++ii) {
    const int gr = m0 + wr * 64 + ii * 16 + ro * 4;
#pragma unroll
    for (int j = 0; j < 3; ++j) {
      const int gc = n0 + wc * 48 + j * 16 + lq;
      const float bv = b_o[gc];
#pragma unroll
      for (int r = 0; r < 4; ++r) {
        size_t off = (size_t)(gr + r) * HID_D + gc;
        out[off] = acc[ii][j][r] + bv + x[off];
      }
    }
  }
}

// ---------------- fused YaRN RoPE (blocks 0..18431) + V transpose (blocks 18432..18687) ----------------
__global__ __launch_bounds__(256) void ropevt_kernel(const unsigned short* __restrict__ qkvb,
                                                     const int* __restrict__ positions,
                                                     unsigned short* __restrict__ qb,
                                                     unsigned short* __restrict__ kb,
                                                     unsigned short* __restrict__ vt) {
  __shared__ unsigned short tile[64][72];
  if (blockIdx.x >= ROPE_BLKS) {
    const int vb = blockIdx.x - ROPE_BLKS;
    const int g = vb >> 5;
    const int t0 = (vb & 31) << 6;
    const int r = threadIdx.x >> 3;
    const int c8 = (threadIdx.x & 7) << 3;
    const size_t vbase = (size_t)(NH + NKV) * HD + (size_t)g * HD;
#pragma unroll
    for (int hh = 0; hh < 2; ++hh) {
      int row = r + hh * 32;
      *(u16x8*)&tile[row][c8] =
          *(const u16x8*)(qkvb + (size_t)(t0 + row) * QKV_N + vbase + c8);
    }
    __syncthreads();
    const int d = threadIdx.x >> 2;
    const int ts = (threadIdx.x & 3) << 4;
    u16x8 v0, v1;
#pragma unroll
    for (int i = 0; i < 8; ++i) { v0[i] = tile[ts + i][d]; v1[i] = tile[ts + 8 + i][d]; }
    unsigned short* dst = vt + (size_t)(g * HD + d) * T_SEQ + t0 + ts;
    *(u16x8*)dst = v0;
    *(u16x8*)(dst + 8) = v1;
    return;
  }
  int idx = blockIdx.x * 256 + threadIdx.x;
  int d = idx & 31;
  int head = (idx >> 5) % (NH + NKV);
  int t = idx / ((NH + NKV) * 32);
  float pw = (float)d * (1.0f / 32.0f);
  float extrap = expf(-pw * 11.9183905733f);
  float interp = extrap * (1.0f / 32.0f);
  float ramp = fminf(fmaxf(((float)d - 8.0f) * 0.1f, 0.0f), 1.0f);
  float invf = interp * ramp + extrap * (1.0f - ramp);
  float fr = (float)positions[t] * invf;
  float s, c;
  sincosf(fr, &s, &c);
  c *= MSCALE;
  s *= MSCALE;
  if (head < NH) {
    const unsigned short* b = qkvb + (size_t)t * QKV_N + head * HD + d;
    float x1 = bf2f(b[0]), x2 = bf2f(b[32]);
    unsigned short* ob = qb + (size_t)t * ATT_N + head * HD + d;
    ob[0] = f2bf(x1 * c - x2 * s);
    ob[32] = f2bf(x2 * c + x1 * s);
  } else {
    int gk = head - NH;
    const unsigned short* b = qkvb + (size_t)t * QKV_N + NH * HD + gk * HD + d;
    float x1 = bf2f(b[0]), x2 = bf2f(b[32]);
    unsigned short* ob = kb + (size_t)t * (NKV * HD) + gk * HD + d;
    ob[0] = f2bf(x1 * c - x2 * s);
    ob[32] = f2bf(x2 * c + x1 * s);
  }
}

// ---------------- attention + uniformly-distributed w_o->bf16 conversion ----------------
__global__ __launch_bounds__(256) void attn_kernel(const unsigned short* __restrict__ qb,
                                                   const unsigned short* __restrict__ kb,
                                                   const unsigned short* __restrict__ vt,
                                                   const float* __restrict__ sinks,
                                                   unsigned short* __restrict__ att,
                                                   const float* __restrict__ wo_src,
                                                   unsigned short* __restrict__ wo_dst) {
  __shared__ unsigned short orep[4][16][72];
  {
    const int bid = blockIdx.y * gridDim.x + blockIdx.x;
    const int total = HID_D * 1024;
    for (int i = bid * 256 + threadIdx.x; i < total; i += 2048 * 256) {
      float4 v = ((const float4*)wo_src)[i];
      u16x4 o = { f2bf(v.x), f2bf(v.y), f2bf(v.z), f2bf(v.w) };
      ((u16x4*)wo_dst)[i] = o;
    }
  }
  const int lane = threadIdx.x & 63;
  const int wid = threadIdx.x >> 6;
  const int q0 = blockIdx.x * 16;
  const int h = blockIdx.y * 4 + wid;
  const int g = h >> 3;
  const int lq = lane & 15;
  const int ro = lane >> 4;

  bf16x8 bq0, bq1;
  {
    const unsigned short* qp = qb + (size_t)(q0 + lq) * ATT_N + h * HD + ro * 8;
    bq0 = *(const bf16x8*)qp;
    bq1 = *(const bf16x8*)(qp + 32);
  }
  float m_run = sinks[h];
  float l_run = 1.0f;
  f32x4 o0 = {0.f, 0.f, 0.f, 0.f}, o1 = o0, o2 = o0, o3 = o0;
  const int qg = q0 + lq;
  const int jstart = (q0 >= WIN) ? q0 - WIN : 0;

  for (int jt = jstart; jt <= q0; jt += 32) {
    f32x4 st0 = {0.f, 0.f, 0.f, 0.f}, st1 = st0;
    {
      int kr = jt + ((lq >> 2) << 3) + (lq & 3);
      int kr0 = min(kr, T_SEQ - 1);
      int kr1 = min(kr + 4, T_SEQ - 1);
      const unsigned short* kp0 = kb + (size_t)kr0 * (NKV * HD) + g * HD + ro * 8;
      const unsigned short* kp1 = kb + (size_t)kr1 * (NKV * HD) + g * HD + ro * 8;
      bf16x8 ka0a = *(const bf16x8*)kp0;
      bf16x8 ka0b = *(const bf16x8*)(kp0 + 32);
      bf16x8 ka1a = *(const bf16x8*)kp1;
      bf16x8 ka1b = *(const bf16x8*)(kp1 + 32);
      st0 = __builtin_amdgcn_mfma_f32_16x16x32_bf16(ka0a, bq0, st0, 0, 0, 0);
      st0 = __builtin_amdgcn_mfma_f32_16x16x32_bf16(ka0b, bq1, st0, 0, 0, 0);
      st1 = __builtin_amdgcn_mfma_f32_16x16x32_bf16(ka1a, bq0, st1, 0, 0, 0);
      st1 = __builtin_amdgcn_mfma_f32_16x16x32_bf16(ka1b, bq1, st1, 0, 0, 0);
    }
    float p[8];
    float tmax = -3.0e30f;
#pragma unroll
    for (int r = 0; r < 4; ++r) {
      int jg0 = jt + ro * 8 + r;
      int jg1 = jg0 + 4;
      float s0 = (jg0 <= qg && (qg - jg0) < WIN) ? st0[r] * RSCALE : -3.0e30f;
      float s1 = (jg1 <= qg && (qg - jg1) < WIN) ? st1[r] * RSCALE : -3.0e30f;
      p[r] = s0;
      p[r + 4] = s1;
      tmax = fmaxf(tmax, fmaxf(s0, s1));
    }
    tmax = fmaxf(tmax, __shfl_xor(tmax, 16));
    tmax = fmaxf(tmax, __shfl_xor(tmax, 32));
    float m_new = fmaxf(m_run, tmax);
    float rescale = expf(m_run - m_new);
    float psum = 0.f;
    bf16x8 pa;
#pragma unroll
    for (int jj = 0; jj < 8; ++jj) {
      float pe = expf(p[jj] - m_new);
      psum += pe;
      pa[jj] = (short)f2bf(pe);
    }
    psum += __shfl_xor(psum, 16);
    psum += __shfl_xor(psum, 32);
    l_run = l_run * rescale + psum;
    m_run = m_new;
    f32x4 rs4;
#pragma unroll
    for (int r = 0; r < 4; ++r) rs4[r] = __shfl(rescale, ro * 4 + r);
    o0 *= rs4; o1 *= rs4; o2 *= rs4; o3 *= rs4;
    int tb = jt + ro * 8;
    if (tb > T_SEQ - 8) tb = T_SEQ - 8;
    const unsigned short* vp = vt + (size_t)(g * HD + lq) * T_SEQ + tb;
    bf16x8 v0 = *(const bf16x8*)vp;
    bf16x8 v1 = *(const bf16x8*)(vp + 16 * T_SEQ);
    bf16x8 v2 = *(const bf16x8*)(vp + 32 * T_SEQ);
    bf16x8 v3 = *(const bf16x8*)(vp + 48 * T_SEQ);
    o0 = __builtin_amdgcn_mfma_f32_16x16x32_bf16(pa, v0, o0, 0, 0, 0);
    o1 = __builtin_amdgcn_mfma_f32_16x16x32_bf16(pa, v1, o1, 0, 0, 0);
    o2 = __builtin_amdgcn_mfma_f32_16x16x32_bf16(pa, v2, o2, 0, 0, 0);
    o3 = __builtin_amdgcn_mfma_f32_16x16x32_bf16(pa, v3, o3, 0, 0, 0);
  }

#pragma unroll
  for (int r = 0; r < 4; ++r) {
    float lr = __shfl(l_run, ro * 4 + r);
    float inv = 1.0f / lr;
    int row = ro * 4 + r;
    orep[wid][row][lq]      = f2bf(o0[r] * inv);
    orep[wid][row][lq + 16] = f2bf(o1[r] * inv);
    orep[wid][row][lq + 32] = f2bf(o2[r] * inv);
    orep[wid][row][lq + 48] = f2bf(o3[r] * inv);
  }
  {
    const int row = lane >> 2;
    const int seg = (lane & 3) << 4;
    u16x8 w0 = *(const u16x8*)&orep[wid][row][seg];
    u16x8 w1 = *(const u16x8*)&orep[wid][row][seg + 8];
    unsigned short* op = att + (size_t)(q0 + row) * ATT_N + h * HD + seg;
    *(u16x8*)op = w0;
    *(u16x8*)(op + 8) = w1;
  }
}

extern "C" void kernel_launch(void* const* d_in, const int* in_sizes, int n_in,
                              void* d_out, int out_size, void* d_ws, size_t ws_size,
                              hipStream_t stream) {
  const float* x = (const float*)d_in[0];
  const int* pos = (const int*)d_in[1];
  const float* norm_w = (const float*)d_in[2];
  const float* w_qkv = (const float*)d_in[3];
  const float* b_qkv = (const float*)d_in[4];
  const float* w_o = (const float*)d_in[5];
  const float* b_o = (const float*)d_in[6];
  const float* sinks = (const float*)d_in[7];
  float* out = (float*)d_out;

  unsigned short* t_bf = (unsigned short*)d_ws;                        // [2048][2944]
  unsigned short* wq_bf = t_bf + (size_t)T_SEQ * KPAD;                 // [5120][2944]
  unsigned short* wo_bf = wq_bf + (size_t)QKV_N * KPAD;                // [2880][4096] (region sized NOPAD)
  unsigned short* qkv_bf = wo_bf + (size_t)NOPAD * ATT_N;              // [2048][5120] bf16
  unsigned short* qb = qkv_bf + (size_t)T_SEQ * QKV_N;                 // [2048][4096]
  unsigned short* kb = qb + (size_t)T_SEQ * ATT_N;                     // [2048][512]
  unsigned short* vt = kb + (size_t)T_SEQ * NKV * HD;                  // [8][64][2048]
  unsigned short* att = vt + (size_t)NKV * HD * T_SEQ;                 // [2048][4096]

  // 1. RMSNorm + w_qkv conversion
  pre_kernel<<<3072, 256, 0, stream>>>(x, norm_w, t_bf, w_qkv, wq_bf);
  // 2. QKV GEMM: 128x320, 256 blocks (full chip)
  qkv320_kernel<<<256, 512, 0, stream>>>(t_bf, wq_bf, qkv_bf, b_qkv);
  // 3. RoPE (q,k) + V transpose, one launch
  ropevt_kernel<<<ROPE_BLKS + 256, 256, 0, stream>>>(qkv_bf, pos, qb, kb, vt);
  // 4. attention + distributed w_o conversion (must precede outproj)
  attn_kernel<<<dim3(T_SEQ / 16, NH / 4), 256, 0, stream>>>(qb, kb, vt, sinks, att, w_o, wo_bf);
  // 5. out projection: single-phase 3-buf 128x192 tiles, counted vmcnt(5), 240 blocks
  outproj192_kernel<<<240, 512, 0, stream>>>(att, wo_bf, out, b_o, x);
}

// Round 20
// 217.847 us; speedup vs baseline: 1.0830x; 1.0020x over previous
//
#include <hip/hip_runtime.h>
#include <hip/hip_bf16.h>
#include <stdint.h>

typedef __attribute__((ext_vector_type(8))) short bf16x8;
typedef __attribute__((ext_vector_type(8))) unsigned short u16x8;
typedef __attribute__((ext_vector_type(4))) float f32x4;
typedef __attribute__((ext_vector_type(4))) unsigned short u16x4;

#define T_SEQ 2048
#define HID_D 2880
#define KPAD 2944              // 2880 padded to 46*64
#define NH 64
#define NKV 8
#define HD 64
#define QKV_N 5120
#define ATT_N 4096
#define NOPAD 3072             // wo_bf region rows (layout constant)
#define WIN 128
#define RSCALE 0.125f
#define MSCALE 1.3465735903f
#define ROPE_TOT (T_SEQ * (NH + NKV) * 32)   // 4718592
#define ROPE_BLKS (ROPE_TOT / 256)           // 18432

__device__ __forceinline__ unsigned short f2bf(float f) {
  union { float f; unsigned u; } v; v.f = f;
  unsigned r = v.u + 0x7fffu + ((v.u >> 16) & 1u);
  return (unsigned short)(r >> 16);
}
__device__ __forceinline__ float bf2f(unsigned short u) {
  union { unsigned u; float f; } v; v.u = ((unsigned)u) << 16;
  return v.f;
}

__device__ __forceinline__ void gload_lds16(const void* g, void* l) {
  __builtin_amdgcn_global_load_lds((const __attribute__((address_space(1))) char*)g,
                                   (__attribute__((address_space(3))) char*)l, 16, 0, 0);
}

// Phase-enter: barrier + setprio only (compiler inserts fine-grained lgkmcnt).
#define GPH_MID()                                        \
  __builtin_amdgcn_s_barrier();                          \
  __builtin_amdgcn_s_setprio(1)
#define GPH_END()                                        \
  __builtin_amdgcn_s_setprio(0);                         \
  __builtin_amdgcn_s_barrier()

// ---- RMSNorm (blocks 0..2047) + w_qkv->bf16 pad (2048..3071) + RoPE trig table (3072..3135) ----
__global__ __launch_bounds__(256) void pre_kernel(const float* __restrict__ x,
                                                  const float* __restrict__ w,
                                                  unsigned short* __restrict__ t_bf,
                                                  const float* __restrict__ wq_src,
                                                  unsigned short* __restrict__ wq_dst,
                                                  const int* __restrict__ positions,
                                                  float2* __restrict__ rtab) {
  __shared__ float red[256];
  if (blockIdx.x < 2048) {
    int row = blockIdx.x;
    const float4* xr4 = (const float4*)(x + (size_t)row * HID_D);
    const float4* w4 = (const float4*)w;
    float ss = 0.f;
    for (int i = threadIdx.x; i < 720; i += 256) {
      float4 v = xr4[i];
      ss += v.x * v.x + v.y * v.y + v.z * v.z + v.w * v.w;
    }
    red[threadIdx.x] = ss;
    __syncthreads();
    for (int s = 128; s > 0; s >>= 1) {
      if (threadIdx.x < s) red[threadIdx.x] += red[threadIdx.x + s];
      __syncthreads();
    }
    float rs = rsqrtf(red[0] / (float)HID_D + 1e-5f);
    u16x4* ob = (u16x4*)(t_bf + (size_t)row * KPAD);
    for (int i = threadIdx.x; i < 736; i += 256) {
      u16x4 o = {0, 0, 0, 0};
      if (i < 720) {
        float4 v = xr4[i];
        float4 g = w4[i];
        o = { f2bf(v.x * rs * g.x), f2bf(v.y * rs * g.y),
              f2bf(v.z * rs * g.z), f2bf(v.w * rs * g.w) };
      }
      ob[i] = o;
    }
  } else if (blockIdx.x < 3072) {
    const int total = QKV_N * 736;
    for (int i = (blockIdx.x - 2048) * 256 + threadIdx.x; i < total; i += 1024 * 256) {
      int c4 = i % 736, row = i / 736;
      u16x4 o = {0, 0, 0, 0};
      if (c4 < 720) {
        float4 v = ((const float4*)wq_src)[(size_t)row * 720 + c4];
        o = { f2bf(v.x), f2bf(v.y), f2bf(v.z), f2bf(v.w) };
      }
      ((u16x4*)wq_dst)[i] = o;
    }
  } else {
    // RoPE trig table: rtab[t*32+d] = (cos, sin)(pos[t]*invf(d)) * MSCALE
    for (int e = (blockIdx.x - 3072) * 256 + threadIdx.x; e < T_SEQ * 32; e += 64 * 256) {
      int d = e & 31, t = e >> 5;
      float pw = (float)d * (1.0f / 32.0f);
      float extrap = expf(-pw * 11.9183905733f);
      float interp = extrap * (1.0f / 32.0f);
      float ramp = fminf(fmaxf(((float)d - 8.0f) * 0.1f, 0.0f), 1.0f);
      float invf = interp * ramp + extrap * (1.0f - ramp);
      float fr = (float)positions[t] * invf;
      float s, c;
      sincosf(fr, &s, &c);
      rtab[e] = make_float2(c * MSCALE, s * MSCALE);
    }
  }
}

// ============ QKV GEMM: 128x320 tile, 256 blocks (16Mx16N), FULL K=2944 ============
__global__ __launch_bounds__(512, 2) void qkv320_kernel(const unsigned short* __restrict__ A,
                                                        const unsigned short* __restrict__ B,
                                                        unsigned short* __restrict__ C,
                                                        const float* __restrict__ bias) {
  __shared__ unsigned short sA[2 * 128 * 64];       // 32 KiB
  __shared__ unsigned short sB[3 * 320 * 64];       // 120 KiB

  const int tid = threadIdx.x;
  const int lane = tid & 63, wid = tid >> 6;
  const int wr = wid >> 2, wc = wid & 3;            // 2M x 4N waves: 64x80 each
  const int lq = lane & 15, ro = lane >> 4;

  const int c = blockIdx.x & 7, q = blockIdx.x >> 3;      // q: 0..31
  const int by = (c & 1) * 8 + (q & 7);
  const int bx = (c >> 1) * 4 + (q >> 3);
  const int m0 = by * 128, n0 = bx * 320;

  const int R0 = tid >> 3;
  const int g0 = (((tid & 7) ^ (R0 & 7)) << 3);
  const size_t aOff = (size_t)(m0 + R0) * KPAD + g0;
  size_t bOff[5];
#pragma unroll
  for (int r = 0; r < 5; ++r)
    bOff[r] = (size_t)(n0 + r * 64 + R0) * KPAD + g0;

  const int ck0 = ((ro ^ (lq & 7)) << 3);
  const int ck1 = (((4 + ro) ^ (lq & 7)) << 3);

#define QSTG_A(BUF, KT)                                                         \
  { unsigned short* _d = sA + (BUF) * 8192 + wid * 512;                         \
    const unsigned short* _s = A + aOff + (size_t)(KT) * 64;                    \
    gload_lds16(_s, _d); gload_lds16(_s + (size_t)64 * KPAD, _d + 4096); }
#define QSTG_B(BUF, KT)                                                         \
  { unsigned short* _d = sB + (BUF) * 20480 + wid * 512;                        \
    gload_lds16(B + bOff[0] + (KT) * 64, _d);                                   \
    gload_lds16(B + bOff[1] + (KT) * 64, _d + 4096);                            \
    gload_lds16(B + bOff[2] + (KT) * 64, _d + 8192);                            \
    gload_lds16(B + bOff[3] + (KT) * 64, _d + 12288);                           \
    gload_lds16(B + bOff[4] + (KT) * 64, _d + 16384); }

  bf16x8 aR[8];
  bf16x8 b00, b01, b10, b11, b20, b21, b30, b31, b40, b41;
  f32x4 acc[4][5] = {};

#define QLDA(BUF)                                                                          \
  { _Pragma("unroll") for (int ii = 0; ii < 4; ++ii) {                                     \
      const int _r = (BUF) * 8192 + (wr * 64 + ii * 16 + lq) * 64;                         \
      aR[ii * 2 + 0] = *(const bf16x8*)&sA[_r + ck0];                                      \
      aR[ii * 2 + 1] = *(const bf16x8*)&sA[_r + ck1]; } }
#define QLDB(BUF, J, D0, D1)                                                               \
  { const int _r = (BUF) * 20480 + (wc * 80 + (J) * 16 + lq) * 64;                         \
    D0 = *(const bf16x8*)&sB[_r + ck0];                                                    \
    D1 = *(const bf16x8*)&sB[_r + ck1]; }
#define QMM(J, B0, B1)                                                                     \
  { _Pragma("unroll") for (int ii = 0; ii < 4; ++ii) {                                     \
      acc[ii][J] = __builtin_amdgcn_mfma_f32_16x16x32_bf16(aR[ii * 2 + 0], B0, acc[ii][J], 0, 0, 0); \
      acc[ii][J] = __builtin_amdgcn_mfma_f32_16x16x32_bf16(aR[ii * 2 + 1], B1, acc[ii][J], 0, 0, 0); } }

  QSTG_B(0, 0); QSTG_A(0, 0);
  QSTG_B(1, 1); QSTG_A(1, 1);
  asm volatile("s_waitcnt vmcnt(7)" ::: "memory");
  __builtin_amdgcn_s_barrier();

  const int nt = 46;
  for (int T = 0; T < nt; ++T) {
    const bool more = (T + 2 < nt);
    const int bb = T % 3, bA = T & 1;
    QLDA(bA);
    QLDB(bb, 0, b00, b01);
    QLDB(bb, 1, b10, b11);
    if (more) QSTG_B((T + 2) % 3, T + 2);
    GPH_MID();
    QMM(0, b00, b01);
    QMM(1, b10, b11);
    GPH_END();
    QLDB(bb, 2, b20, b21);
    QLDB(bb, 3, b30, b31);
    QLDB(bb, 4, b40, b41);
    if (more) QSTG_A((T + 2) & 1, T + 2);
    GPH_MID();
    QMM(2, b20, b21);
    QMM(3, b30, b31);
    QMM(4, b40, b41);
    __builtin_amdgcn_s_setprio(0);
    if (more) asm volatile("s_waitcnt vmcnt(7)" ::: "memory");
    else      asm volatile("s_waitcnt vmcnt(0)" ::: "memory");
    __builtin_amdgcn_s_barrier();
  }
#undef QSTG_A
#undef QSTG_B
#undef QLDA
#undef QLDB
#undef QMM

#pragma unroll
  for (int ii = 0; ii < 4; ++ii) {
    const int gr = m0 + wr * 64 + ii * 16 + ro * 4;
#pragma unroll
    for (int j = 0; j < 5; ++j) {
      const int gc = n0 + wc * 80 + j * 16 + lq;
      const float bv = bias[gc];
#pragma unroll
      for (int r = 0; r < 4; ++r)
        C[(size_t)(gr + r) * QKV_N + gc] = f2bf(acc[ii][j][r] + bv);
    }
  }
}

// ============ out projection: 128x192 tile, FULL K=4096, 240 blocks, SINGLE-PHASE ============
__global__ __launch_bounds__(512, 2) void outproj192_kernel(const unsigned short* __restrict__ att,
                                                            const unsigned short* __restrict__ wo,
                                                            float* __restrict__ out,
                                                            const float* __restrict__ b_o,
                                                            const float* __restrict__ x) {
  __shared__ unsigned short sA[3 * 128 * 64];       // 48 KiB
  __shared__ unsigned short sB[3 * 192 * 64];       // 72 KiB

  const int tid = threadIdx.x;
  const int lane = tid & 63, wid = tid >> 6;
  const int wr = wid >> 2, wc = wid & 3;            // 2M x 4N waves: 64x48 each
  const int lq = lane & 15, ro = lane >> 4;

  const int c = blockIdx.x & 7, q = blockIdx.x >> 3;      // q: 0..29
  const int by = c * 2 + (q >= 15 ? 1 : 0);
  const int bx = (q >= 15) ? q - 15 : q;
  const int m0 = by * 128, n0 = bx * 192;

  const int R0 = tid >> 3;
  const int g0 = (((tid & 7) ^ (R0 & 7)) << 3);
  const size_t aOff = (size_t)(m0 + R0) * ATT_N + g0;
  size_t bOff[3];
#pragma unroll
  for (int r = 0; r < 3; ++r)
    bOff[r] = (size_t)(n0 + r * 64 + R0) * ATT_N + g0;

  const int ck0 = ((ro ^ (lq & 7)) << 3);
  const int ck1 = (((4 + ro) ^ (lq & 7)) << 3);

#define PSTG_A(BUF, KT)                                                         \
  { unsigned short* _d = sA + (BUF) * 8192 + wid * 512;                         \
    const unsigned short* _s = att + aOff + (size_t)(KT) * 64;                  \
    gload_lds16(_s, _d); gload_lds16(_s + (size_t)64 * ATT_N, _d + 4096); }
#define PSTG_B(BUF, KT)                                                         \
  { unsigned short* _d = sB + (BUF) * 12288 + wid * 512;                        \
    gload_lds16(wo + bOff[0] + (KT) * 64, _d);                                  \
    gload_lds16(wo + bOff[1] + (KT) * 64, _d + 4096);                           \
    gload_lds16(wo + bOff[2] + (KT) * 64, _d + 8192); }

  bf16x8 aR[8];
  bf16x8 b00, b01, b10, b11, b20, b21;
  f32x4 acc[4][3] = {};

#define PLDA(BUF)                                                                          \
  { _Pragma("unroll") for (int ii = 0; ii < 4; ++ii) {                                     \
      const int _r = (BUF) * 8192 + (wr * 64 + ii * 16 + lq) * 64;                         \
      aR[ii * 2 + 0] = *(const bf16x8*)&sA[_r + ck0];                                      \
      aR[ii * 2 + 1] = *(const bf16x8*)&sA[_r + ck1]; } }
#define PLDB(BUF, J, D0, D1)                                                               \
  { const int _r = (BUF) * 12288 + (wc * 48 + (J) * 16 + lq) * 64;                         \
    D0 = *(const bf16x8*)&sB[_r + ck0];                                                    \
    D1 = *(const bf16x8*)&sB[_r + ck1]; }

  PSTG_B(0, 0); PSTG_A(0, 0);
  PSTG_B(1, 1); PSTG_A(1, 1);
  asm volatile("s_waitcnt vmcnt(5)" ::: "memory");
  __builtin_amdgcn_s_barrier();

  const int nt = 64;
  for (int T = 0; T < nt; ++T) {
    const bool more = (T + 2 < nt);
    const int bb = T % 3;
    PLDA(bb);
    PLDB(bb, 0, b00, b01);
    PLDB(bb, 1, b10, b11);
    PLDB(bb, 2, b20, b21);
    if (more) { PSTG_B((T + 2) % 3, T + 2); PSTG_A((T + 2) % 3, T + 2); }
    GPH_MID();
#pragma unroll
    for (int ii = 0; ii < 4; ++ii) {
      acc[ii][0] = __builtin_amdgcn_mfma_f32_16x16x32_bf16(aR[ii * 2 + 0], b00, acc[ii][0], 0, 0, 0);
      acc[ii][0] = __builtin_amdgcn_mfma_f32_16x16x32_bf16(aR[ii * 2 + 1], b01, acc[ii][0], 0, 0, 0);
      acc[ii][1] = __builtin_amdgcn_mfma_f32_16x16x32_bf16(aR[ii * 2 + 0], b10, acc[ii][1], 0, 0, 0);
      acc[ii][1] = __builtin_amdgcn_mfma_f32_16x16x32_bf16(aR[ii * 2 + 1], b11, acc[ii][1], 0, 0, 0);
      acc[ii][2] = __builtin_amdgcn_mfma_f32_16x16x32_bf16(aR[ii * 2 + 0], b20, acc[ii][2], 0, 0, 0);
      acc[ii][2] = __builtin_amdgcn_mfma_f32_16x16x32_bf16(aR[ii * 2 + 1], b21, acc[ii][2], 0, 0, 0);
    }
    __builtin_amdgcn_s_setprio(0);
    if (more) asm volatile("s_waitcnt vmcnt(5)" ::: "memory");
    else      asm volatile("s_waitcnt vmcnt(0)" ::: "memory");
    __builtin_amdgcn_s_barrier();
  }
#undef PSTG_A
#undef PSTG_B
#undef PLDA
#undef PLDB

#pragma unroll
  for (int ii = 0; ii < 4; ++ii) {
    const int gr = m0 + wr * 64 + ii * 16 + ro * 4;
#pragma unroll
    for (int j = 0; j < 3; ++j) {
      const int gc = n0 + wc * 48 + j * 16 + lq;
      const float bv = b_o[gc];
#pragma unroll
      for (int r = 0; r < 4; ++r) {
        size_t off = (size_t)(gr + r) * HID_D + gc;
        out[off] = acc[ii][j][r] + bv + x[off];
      }
    }
  }
}

// ---------------- fused RoPE via trig table (blocks 0..18431) + V transpose (18432..18687) ----------------
__global__ __launch_bounds__(256) void ropevt_kernel(const unsigned short* __restrict__ qkvb,
                                                     const float2* __restrict__ rtab,
                                                     unsigned short* __restrict__ qb,
                                                     unsigned short* __restrict__ kb,
                                                     unsigned short* __restrict__ vt) {
  __shared__ unsigned short tile[64][72];
  if (blockIdx.x >= ROPE_BLKS) {
    const int vb = blockIdx.x - ROPE_BLKS;
    const int g = vb >> 5;
    const int t0 = (vb & 31) << 6;
    const int r = threadIdx.x >> 3;
    const int c8 = (threadIdx.x & 7) << 3;
    const size_t vbase = (size_t)(NH + NKV) * HD + (size_t)g * HD;
#pragma unroll
    for (int hh = 0; hh < 2; ++hh) {
      int row = r + hh * 32;
      *(u16x8*)&tile[row][c8] =
          *(const u16x8*)(qkvb + (size_t)(t0 + row) * QKV_N + vbase + c8);
    }
    __syncthreads();
    const int d = threadIdx.x >> 2;
    const int ts = (threadIdx.x & 3) << 4;
    u16x8 v0, v1;
#pragma unroll
    for (int i = 0; i < 8; ++i) { v0[i] = tile[ts + i][d]; v1[i] = tile[ts + 8 + i][d]; }
    unsigned short* dst = vt + (size_t)(g * HD + d) * T_SEQ + t0 + ts;
    *(u16x8*)dst = v0;
    *(u16x8*)(dst + 8) = v1;
    return;
  }
  int idx = blockIdx.x * 256 + threadIdx.x;
  int d = idx & 31;
  int head = (idx >> 5) % (NH + NKV);
  int t = idx / ((NH + NKV) * 32);
  float2 cs = rtab[t * 32 + d];      // (cos*MSCALE, sin*MSCALE)
  if (head < NH) {
    const unsigned short* b = qkvb + (size_t)t * QKV_N + head * HD + d;
    float x1 = bf2f(b[0]), x2 = bf2f(b[32]);
    unsigned short* ob = qb + (size_t)t * ATT_N + head * HD + d;
    ob[0] = f2bf(x1 * cs.x - x2 * cs.y);
    ob[32] = f2bf(x2 * cs.x + x1 * cs.y);
  } else {
    int gk = head - NH;
    const unsigned short* b = qkvb + (size_t)t * QKV_N + NH * HD + gk * HD + d;
    float x1 = bf2f(b[0]), x2 = bf2f(b[32]);
    unsigned short* ob = kb + (size_t)t * (NKV * HD) + gk * HD + d;
    ob[0] = f2bf(x1 * cs.x - x2 * cs.y);
    ob[32] = f2bf(x2 * cs.x + x1 * cs.y);
  }
}

// ---------------- attention + uniformly-distributed w_o->bf16 conversion ----------------
__global__ __launch_bounds__(256) void attn_kernel(const unsigned short* __restrict__ qb,
                                                   const unsigned short* __restrict__ kb,
                                                   const unsigned short* __restrict__ vt,
                                                   const float* __restrict__ sinks,
                                                   unsigned short* __restrict__ att,
                                                   const float* __restrict__ wo_src,
                                                   unsigned short* __restrict__ wo_dst) {
  __shared__ unsigned short orep[4][16][72];
  {
    const int bid = blockIdx.y * gridDim.x + blockIdx.x;
    const int total = HID_D * 1024;
    for (int i = bid * 256 + threadIdx.x; i < total; i += 2048 * 256) {
      float4 v = ((const float4*)wo_src)[i];
      u16x4 o = { f2bf(v.x), f2bf(v.y), f2bf(v.z), f2bf(v.w) };
      ((u16x4*)wo_dst)[i] = o;
    }
  }
  const int lane = threadIdx.x & 63;
  const int wid = threadIdx.x >> 6;
  const int q0 = blockIdx.x * 16;
  const int h = blockIdx.y * 4 + wid;
  const int g = h >> 3;
  const int lq = lane & 15;
  const int ro = lane >> 4;

  bf16x8 bq0, bq1;
  {
    const unsigned short* qp = qb + (size_t)(q0 + lq) * ATT_N + h * HD + ro * 8;
    bq0 = *(const bf16x8*)qp;
    bq1 = *(const bf16x8*)(qp + 32);
  }
  float m_run = sinks[h];
  float l_run = 1.0f;
  f32x4 o0 = {0.f, 0.f, 0.f, 0.f}, o1 = o0, o2 = o0, o3 = o0;
  const int qg = q0 + lq;
  const int jstart = (q0 >= WIN) ? q0 - WIN : 0;

  for (int jt = jstart; jt <= q0; jt += 32) {
    f32x4 st0 = {0.f, 0.f, 0.f, 0.f}, st1 = st0;
    {
      int kr = jt + ((lq >> 2) << 3) + (lq & 3);
      int kr0 = min(kr, T_SEQ - 1);
      int kr1 = min(kr + 4, T_SEQ - 1);
      const unsigned short* kp0 = kb + (size_t)kr0 * (NKV * HD) + g * HD + ro * 8;
      const unsigned short* kp1 = kb + (size_t)kr1 * (NKV * HD) + g * HD + ro * 8;
      bf16x8 ka0a = *(const bf16x8*)kp0;
      bf16x8 ka0b = *(const bf16x8*)(kp0 + 32);
      bf16x8 ka1a = *(const bf16x8*)kp1;
      bf16x8 ka1b = *(const bf16x8*)(kp1 + 32);
      st0 = __builtin_amdgcn_mfma_f32_16x16x32_bf16(ka0a, bq0, st0, 0, 0, 0);
      st0 = __builtin_amdgcn_mfma_f32_16x16x32_bf16(ka0b, bq1, st0, 0, 0, 0);
      st1 = __builtin_amdgcn_mfma_f32_16x16x32_bf16(ka1a, bq0, st1, 0, 0, 0);
      st1 = __builtin_amdgcn_mfma_f32_16x16x32_bf16(ka1b, bq1, st1, 0, 0, 0);
    }
    float p[8];
    float tmax = -3.0e30f;
#pragma unroll
    for (int r = 0; r < 4; ++r) {
      int jg0 = jt + ro * 8 + r;
      int jg1 = jg0 + 4;
      float s0 = (jg0 <= qg && (qg - jg0) < WIN) ? st0[r] * RSCALE : -3.0e30f;
      float s1 = (jg1 <= qg && (qg - jg1) < WIN) ? st1[r] * RSCALE : -3.0e30f;
      p[r] = s0;
      p[r + 4] = s1;
      tmax = fmaxf(tmax, fmaxf(s0, s1));
    }
    tmax = fmaxf(tmax, __shfl_xor(tmax, 16));
    tmax = fmaxf(tmax, __shfl_xor(tmax, 32));
    float m_new = fmaxf(m_run, tmax);
    float rescale = expf(m_run - m_new);
    float psum = 0.f;
    bf16x8 pa;
#pragma unroll
    for (int jj = 0; jj < 8; ++jj) {
      float pe = expf(p[jj] - m_new);
      psum += pe;
      pa[jj] = (short)f2bf(pe);
    }
    psum += __shfl_xor(psum, 16);
    psum += __shfl_xor(psum, 32);
    l_run = l_run * rescale + psum;
    m_run = m_new;
    f32x4 rs4;
#pragma unroll
    for (int r = 0; r < 4; ++r) rs4[r] = __shfl(rescale, ro * 4 + r);
    o0 *= rs4; o1 *= rs4; o2 *= rs4; o3 *= rs4;
    int tb = jt + ro * 8;
    if (tb > T_SEQ - 8) tb = T_SEQ - 8;
    const unsigned short* vp = vt + (size_t)(g * HD + lq) * T_SEQ + tb;
    bf16x8 v0 = *(const bf16x8*)vp;
    bf16x8 v1 = *(const bf16x8*)(vp + 16 * T_SEQ);
    bf16x8 v2 = *(const bf16x8*)(vp + 32 * T_SEQ);
    bf16x8 v3 = *(const bf16x8*)(vp + 48 * T_SEQ);
    o0 = __builtin_amdgcn_mfma_f32_16x16x32_bf16(pa, v0, o0, 0, 0, 0);
    o1 = __builtin_amdgcn_mfma_f32_16x16x32_bf16(pa, v1, o1, 0, 0, 0);
    o2 = __builtin_amdgcn_mfma_f32_16x16x32_bf16(pa, v2, o2, 0, 0, 0);
    o3 = __builtin_amdgcn_mfma_f32_16x16x32_bf16(pa, v3, o3, 0, 0, 0);
  }

#pragma unroll
  for (int r = 0; r < 4; ++r) {
    float lr = __shfl(l_run, ro * 4 + r);
    float inv = 1.0f / lr;
    int row = ro * 4 + r;
    orep[wid][row][lq]      = f2bf(o0[r] * inv);
    orep[wid][row][lq + 16] = f2bf(o1[r] * inv);
    orep[wid][row][lq + 32] = f2bf(o2[r] * inv);
    orep[wid][row][lq + 48] = f2bf(o3[r] * inv);
  }
  {
    const int row = lane >> 2;
    const int seg = (lane & 3) << 4;
    u16x8 w0 = *(const u16x8*)&orep[wid][row][seg];
    u16x8 w1 = *(const u16x8*)&orep[wid][row][seg + 8];
    unsigned short* op = att + (size_t)(q0 + row) * ATT_N + h * HD + seg;
    *(u16x8*)op = w0;
    *(u16x8*)(op + 8) = w1;
  }
}

extern "C" void kernel_launch(void* const* d_in, const int* in_sizes, int n_in,
                              void* d_out, int out_size, void* d_ws, size_t ws_size,
                              hipStream_t stream) {
  const float* x = (const float*)d_in[0];
  const int* pos = (const int*)d_in[1];
  const float* norm_w = (const float*)d_in[2];
  const float* w_qkv = (const float*)d_in[3];
  const float* b_qkv = (const float*)d_in[4];
  const float* w_o = (const float*)d_in[5];
  const float* b_o = (const float*)d_in[6];
  const float* sinks = (const float*)d_in[7];
  float* out = (float*)d_out;

  unsigned short* t_bf = (unsigned short*)d_ws;                        // [2048][2944]
  unsigned short* wq_bf = t_bf + (size_t)T_SEQ * KPAD;                 // [5120][2944]
  unsigned short* wo_bf = wq_bf + (size_t)QKV_N * KPAD;                // [2880][4096] (region sized NOPAD)
  unsigned short* qkv_bf = wo_bf + (size_t)NOPAD * ATT_N;              // [2048][5120] bf16
  unsigned short* qb = qkv_bf + (size_t)T_SEQ * QKV_N;                 // [2048][4096]
  unsigned short* kb = qb + (size_t)T_SEQ * ATT_N;                     // [2048][512]
  unsigned short* vt = kb + (size_t)T_SEQ * NKV * HD;                  // [8][64][2048]
  unsigned short* att = vt + (size_t)NKV * HD * T_SEQ;                 // [2048][4096]
  float2* rtab = (float2*)(att + (size_t)T_SEQ * ATT_N);               // [2048][32] (cos,sin)

  // 1. RMSNorm + w_qkv conversion + RoPE trig table
  pre_kernel<<<3136, 256, 0, stream>>>(x, norm_w, t_bf, w_qkv, wq_bf, pos, rtab);
  // 2. QKV GEMM: 128x320, 256 blocks (full chip)
  qkv320_kernel<<<256, 512, 0, stream>>>(t_bf, wq_bf, qkv_bf, b_qkv);
  // 3. RoPE (table-driven) + V transpose, one launch
  ropevt_kernel<<<ROPE_BLKS + 256, 256, 0, stream>>>(qkv_bf, rtab, qb, kb, vt);
  // 4. attention + distributed w_o conversion (must precede outproj)
  attn_kernel<<<dim3(T_SEQ / 16, NH / 4), 256, 0, stream>>>(qb, kb, vt, sinks, att, w_o, wo_bf);
  // 5. out projection: single-phase 3-buf 128x192 tiles, counted vmcnt(5), 240 blocks
  outproj192_kernel<<<240, 512, 0, stream>>>(att, wo_bf, out, b_o, x);
}

// Round 21
// 213.520 us; speedup vs baseline: 1.1049x; 1.0203x over previous
//
#include <hip/hip_runtime.h>
#include <hip/hip_bf16.h>
#include <stdint.h>

typedef __attribute__((ext_vector_type(8))) short bf16x8;
typedef __attribute__((ext_vector_type(8))) unsigned short u16x8;
typedef __attribute__((ext_vector_type(4))) float f32x4;
typedef __attribute__((ext_vector_type(4))) unsigned short u16x4;

#define T_SEQ 2048
#define HID_D 2880
#define KPAD 2944              // 2880 padded to 46*64
#define NH 64
#define NKV 8
#define HD 64
#define QKV_N 5120
#define ATT_N 4096
#define NOPAD 3072             // wo_bf region rows (layout constant)
#define WIN 128
#define RSCALE 0.125f
#define MSCALE 1.3465735903f
#define ROPE_BLKS (T_SEQ * (NH + NKV) * 4 / 256)   // 2304 (one thread per 8-dim group)

__device__ __forceinline__ unsigned short f2bf(float f) {
  union { float f; unsigned u; } v; v.f = f;
  unsigned r = v.u + 0x7fffu + ((v.u >> 16) & 1u);
  return (unsigned short)(r >> 16);
}
__device__ __forceinline__ float bf2f(unsigned short u) {
  union { unsigned u; float f; } v; v.u = ((unsigned)u) << 16;
  return v.f;
}

__device__ __forceinline__ void gload_lds16(const void* g, void* l) {
  __builtin_amdgcn_global_load_lds((const __attribute__((address_space(1))) char*)g,
                                   (__attribute__((address_space(3))) char*)l, 16, 0, 0);
}

// Phase-enter: barrier + setprio only (compiler inserts fine-grained lgkmcnt).
#define GPH_MID()                                        \
  __builtin_amdgcn_s_barrier();                          \
  __builtin_amdgcn_s_setprio(1)
#define GPH_END()                                        \
  __builtin_amdgcn_s_setprio(0);                         \
  __builtin_amdgcn_s_barrier()

// ---- RMSNorm (blocks 0..2047) + w_qkv->bf16 pad (2048..3071) + RoPE trig table (3072..3135) ----
__global__ __launch_bounds__(256) void pre_kernel(const float* __restrict__ x,
                                                  const float* __restrict__ w,
                                                  unsigned short* __restrict__ t_bf,
                                                  const float* __restrict__ wq_src,
                                                  unsigned short* __restrict__ wq_dst,
                                                  const int* __restrict__ positions,
                                                  float2* __restrict__ rtab) {
  __shared__ float red[256];
  if (blockIdx.x < 2048) {
    int row = blockIdx.x;
    const float4* xr4 = (const float4*)(x + (size_t)row * HID_D);
    const float4* w4 = (const float4*)w;
    float ss = 0.f;
    for (int i = threadIdx.x; i < 720; i += 256) {
      float4 v = xr4[i];
      ss += v.x * v.x + v.y * v.y + v.z * v.z + v.w * v.w;
    }
    red[threadIdx.x] = ss;
    __syncthreads();
    for (int s = 128; s > 0; s >>= 1) {
      if (threadIdx.x < s) red[threadIdx.x] += red[threadIdx.x + s];
      __syncthreads();
    }
    float rs = rsqrtf(red[0] / (float)HID_D + 1e-5f);
    u16x4* ob = (u16x4*)(t_bf + (size_t)row * KPAD);
    for (int i = threadIdx.x; i < 736; i += 256) {
      u16x4 o = {0, 0, 0, 0};
      if (i < 720) {
        float4 v = xr4[i];
        float4 g = w4[i];
        o = { f2bf(v.x * rs * g.x), f2bf(v.y * rs * g.y),
              f2bf(v.z * rs * g.z), f2bf(v.w * rs * g.w) };
      }
      ob[i] = o;
    }
  } else if (blockIdx.x < 3072) {
    const int total = QKV_N * 736;
    for (int i = (blockIdx.x - 2048) * 256 + threadIdx.x; i < total; i += 1024 * 256) {
      int c4 = i % 736, row = i / 736;
      u16x4 o = {0, 0, 0, 0};
      if (c4 < 720) {
        float4 v = ((const float4*)wq_src)[(size_t)row * 720 + c4];
        o = { f2bf(v.x), f2bf(v.y), f2bf(v.z), f2bf(v.w) };
      }
      ((u16x4*)wq_dst)[i] = o;
    }
  } else {
    // RoPE trig table: rtab[t*32+d] = (cos, sin)(pos[t]*invf(d)) * MSCALE
    for (int e = (blockIdx.x - 3072) * 256 + threadIdx.x; e < T_SEQ * 32; e += 64 * 256) {
      int d = e & 31, t = e >> 5;
      float pw = (float)d * (1.0f / 32.0f);
      float extrap = expf(-pw * 11.9183905733f);
      float interp = extrap * (1.0f / 32.0f);
      float ramp = fminf(fmaxf(((float)d - 8.0f) * 0.1f, 0.0f), 1.0f);
      float invf = interp * ramp + extrap * (1.0f - ramp);
      float fr = (float)positions[t] * invf;
      float s, c;
      sincosf(fr, &s, &c);
      rtab[e] = make_float2(c * MSCALE, s * MSCALE);
    }
  }
}

// ============ QKV GEMM: 128x320 tile, 256 blocks (16Mx16N), FULL K=2944 ============
__global__ __launch_bounds__(512, 2) void qkv320_kernel(const unsigned short* __restrict__ A,
                                                        const unsigned short* __restrict__ B,
                                                        unsigned short* __restrict__ C,
                                                        const float* __restrict__ bias) {
  __shared__ unsigned short sA[2 * 128 * 64];       // 32 KiB
  __shared__ unsigned short sB[3 * 320 * 64];       // 120 KiB

  const int tid = threadIdx.x;
  const int lane = tid & 63, wid = tid >> 6;
  const int wr = wid >> 2, wc = wid & 3;            // 2M x 4N waves: 64x80 each
  const int lq = lane & 15, ro = lane >> 4;

  const int c = blockIdx.x & 7, q = blockIdx.x >> 3;      // q: 0..31
  const int by = (c & 1) * 8 + (q & 7);
  const int bx = (c >> 1) * 4 + (q >> 3);
  const int m0 = by * 128, n0 = bx * 320;

  const int R0 = tid >> 3;
  const int g0 = (((tid & 7) ^ (R0 & 7)) << 3);
  const size_t aOff = (size_t)(m0 + R0) * KPAD + g0;
  size_t bOff[5];
#pragma unroll
  for (int r = 0; r < 5; ++r)
    bOff[r] = (size_t)(n0 + r * 64 + R0) * KPAD + g0;

  const int ck0 = ((ro ^ (lq & 7)) << 3);
  const int ck1 = (((4 + ro) ^ (lq & 7)) << 3);

#define QSTG_A(BUF, KT)                                                         \
  { unsigned short* _d = sA + (BUF) * 8192 + wid * 512;                         \
    const unsigned short* _s = A + aOff + (size_t)(KT) * 64;                    \
    gload_lds16(_s, _d); gload_lds16(_s + (size_t)64 * KPAD, _d + 4096); }
#define QSTG_B(BUF, KT)                                                         \
  { unsigned short* _d = sB + (BUF) * 20480 + wid * 512;                        \
    gload_lds16(B + bOff[0] + (KT) * 64, _d);                                   \
    gload_lds16(B + bOff[1] + (KT) * 64, _d + 4096);                            \
    gload_lds16(B + bOff[2] + (KT) * 64, _d + 8192);                            \
    gload_lds16(B + bOff[3] + (KT) * 64, _d + 12288);                           \
    gload_lds16(B + bOff[4] + (KT) * 64, _d + 16384); }

  bf16x8 aR[8];
  bf16x8 b00, b01, b10, b11, b20, b21, b30, b31, b40, b41;
  f32x4 acc[4][5] = {};

#define QLDA(BUF)                                                                          \
  { _Pragma("unroll") for (int ii = 0; ii < 4; ++ii) {                                     \
      const int _r = (BUF) * 8192 + (wr * 64 + ii * 16 + lq) * 64;                         \
      aR[ii * 2 + 0] = *(const bf16x8*)&sA[_r + ck0];                                      \
      aR[ii * 2 + 1] = *(const bf16x8*)&sA[_r + ck1]; } }
#define QLDB(BUF, J, D0, D1)                                                               \
  { const int _r = (BUF) * 20480 + (wc * 80 + (J) * 16 + lq) * 64;                         \
    D0 = *(const bf16x8*)&sB[_r + ck0];                                                    \
    D1 = *(const bf16x8*)&sB[_r + ck1]; }
#define QMM(J, B0, B1)                                                                     \
  { _Pragma("unroll") for (int ii = 0; ii < 4; ++ii) {                                     \
      acc[ii][J] = __builtin_amdgcn_mfma_f32_16x16x32_bf16(aR[ii * 2 + 0], B0, acc[ii][J], 0, 0, 0); \
      acc[ii][J] = __builtin_amdgcn_mfma_f32_16x16x32_bf16(aR[ii * 2 + 1], B1, acc[ii][J], 0, 0, 0); } }

  QSTG_B(0, 0); QSTG_A(0, 0);
  QSTG_B(1, 1); QSTG_A(1, 1);
  asm volatile("s_waitcnt vmcnt(7)" ::: "memory");
  __builtin_amdgcn_s_barrier();

  const int nt = 46;
  for (int T = 0; T < nt; ++T) {
    const bool more = (T + 2 < nt);
    const int bb = T % 3, bA = T & 1;
    QLDA(bA);
    QLDB(bb, 0, b00, b01);
    QLDB(bb, 1, b10, b11);
    if (more) QSTG_B((T + 2) % 3, T + 2);
    GPH_MID();
    QMM(0, b00, b01);
    QMM(1, b10, b11);
    GPH_END();
    QLDB(bb, 2, b20, b21);
    QLDB(bb, 3, b30, b31);
    QLDB(bb, 4, b40, b41);
    if (more) QSTG_A((T + 2) & 1, T + 2);
    GPH_MID();
    QMM(2, b20, b21);
    QMM(3, b30, b31);
    QMM(4, b40, b41);
    __builtin_amdgcn_s_setprio(0);
    if (more) asm volatile("s_waitcnt vmcnt(7)" ::: "memory");
    else      asm volatile("s_waitcnt vmcnt(0)" ::: "memory");
    __builtin_amdgcn_s_barrier();
  }
#undef QSTG_A
#undef QSTG_B
#undef QLDA
#undef QLDB
#undef QMM

#pragma unroll
  for (int ii = 0; ii < 4; ++ii) {
    const int gr = m0 + wr * 64 + ii * 16 + ro * 4;
#pragma unroll
    for (int j = 0; j < 5; ++j) {
      const int gc = n0 + wc * 80 + j * 16 + lq;
      const float bv = bias[gc];
#pragma unroll
      for (int r = 0; r < 4; ++r)
        C[(size_t)(gr + r) * QKV_N + gc] = f2bf(acc[ii][j][r] + bv);
    }
  }
}

// ============ out projection: 128x192 tile, FULL K=4096, 240 blocks, SINGLE-PHASE ============
__global__ __launch_bounds__(512, 2) void outproj192_kernel(const unsigned short* __restrict__ att,
                                                            const unsigned short* __restrict__ wo,
                                                            float* __restrict__ out,
                                                            const float* __restrict__ b_o,
                                                            const float* __restrict__ x) {
  __shared__ unsigned short sA[3 * 128 * 64];       // 48 KiB
  __shared__ unsigned short sB[3 * 192 * 64];       // 72 KiB

  const int tid = threadIdx.x;
  const int lane = tid & 63, wid = tid >> 6;
  const int wr = wid >> 2, wc = wid & 3;            // 2M x 4N waves: 64x48 each
  const int lq = lane & 15, ro = lane >> 4;

  const int c = blockIdx.x & 7, q = blockIdx.x >> 3;      // q: 0..29
  const int by = c * 2 + (q >= 15 ? 1 : 0);
  const int bx = (q >= 15) ? q - 15 : q;
  const int m0 = by * 128, n0 = bx * 192;

  const int R0 = tid >> 3;
  const int g0 = (((tid & 7) ^ (R0 & 7)) << 3);
  const size_t aOff = (size_t)(m0 + R0) * ATT_N + g0;
  size_t bOff[3];
#pragma unroll
  for (int r = 0; r < 3; ++r)
    bOff[r] = (size_t)(n0 + r * 64 + R0) * ATT_N + g0;

  const int ck0 = ((ro ^ (lq & 7)) << 3);
  const int ck1 = (((4 + ro) ^ (lq & 7)) << 3);

#define PSTG_A(BUF, KT)                                                         \
  { unsigned short* _d = sA + (BUF) * 8192 + wid * 512;                         \
    const unsigned short* _s = att + aOff + (size_t)(KT) * 64;                  \
    gload_lds16(_s, _d); gload_lds16(_s + (size_t)64 * ATT_N, _d + 4096); }
#define PSTG_B(BUF, KT)                                                         \
  { unsigned short* _d = sB + (BUF) * 12288 + wid * 512;                        \
    gload_lds16(wo + bOff[0] + (KT) * 64, _d);                                  \
    gload_lds16(wo + bOff[1] + (KT) * 64, _d + 4096);                           \
    gload_lds16(wo + bOff[2] + (KT) * 64, _d + 8192); }

  bf16x8 aR[8];
  bf16x8 b00, b01, b10, b11, b20, b21;
  f32x4 acc[4][3] = {};

#define PLDA(BUF)                                                                          \
  { _Pragma("unroll") for (int ii = 0; ii < 4; ++ii) {                                     \
      const int _r = (BUF) * 8192 + (wr * 64 + ii * 16 + lq) * 64;                         \
      aR[ii * 2 + 0] = *(const bf16x8*)&sA[_r + ck0];                                      \
      aR[ii * 2 + 1] = *(const bf16x8*)&sA[_r + ck1]; } }
#define PLDB(BUF, J, D0, D1)                                                               \
  { const int _r = (BUF) * 12288 + (wc * 48 + (J) * 16 + lq) * 64;                         \
    D0 = *(const bf16x8*)&sB[_r + ck0];                                                    \
    D1 = *(const bf16x8*)&sB[_r + ck1]; }

  PSTG_B(0, 0); PSTG_A(0, 0);
  PSTG_B(1, 1); PSTG_A(1, 1);
  asm volatile("s_waitcnt vmcnt(5)" ::: "memory");
  __builtin_amdgcn_s_barrier();

  const int nt = 64;
  for (int T = 0; T < nt; ++T) {
    const bool more = (T + 2 < nt);
    const int bb = T % 3;
    PLDA(bb);
    PLDB(bb, 0, b00, b01);
    PLDB(bb, 1, b10, b11);
    PLDB(bb, 2, b20, b21);
    if (more) { PSTG_B((T + 2) % 3, T + 2); PSTG_A((T + 2) % 3, T + 2); }
    GPH_MID();
#pragma unroll
    for (int ii = 0; ii < 4; ++ii) {
      acc[ii][0] = __builtin_amdgcn_mfma_f32_16x16x32_bf16(aR[ii * 2 + 0], b00, acc[ii][0], 0, 0, 0);
      acc[ii][0] = __builtin_amdgcn_mfma_f32_16x16x32_bf16(aR[ii * 2 + 1], b01, acc[ii][0], 0, 0, 0);
      acc[ii][1] = __builtin_amdgcn_mfma_f32_16x16x32_bf16(aR[ii * 2 + 0], b10, acc[ii][1], 0, 0, 0);
      acc[ii][1] = __builtin_amdgcn_mfma_f32_16x16x32_bf16(aR[ii * 2 + 1], b11, acc[ii][1], 0, 0, 0);
      acc[ii][2] = __builtin_amdgcn_mfma_f32_16x16x32_bf16(aR[ii * 2 + 0], b20, acc[ii][2], 0, 0, 0);
      acc[ii][2] = __builtin_amdgcn_mfma_f32_16x16x32_bf16(aR[ii * 2 + 1], b21, acc[ii][2], 0, 0, 0);
    }
    __builtin_amdgcn_s_setprio(0);
    if (more) asm volatile("s_waitcnt vmcnt(5)" ::: "memory");
    else      asm volatile("s_waitcnt vmcnt(0)" ::: "memory");
    __builtin_amdgcn_s_barrier();
  }
#undef PSTG_A
#undef PSTG_B
#undef PLDA
#undef PLDB

#pragma unroll
  for (int ii = 0; ii < 4; ++ii) {
    const int gr = m0 + wr * 64 + ii * 16 + ro * 4;
#pragma unroll
    for (int j = 0; j < 3; ++j) {
      const int gc = n0 + wc * 48 + j * 16 + lq;
      const float bv = b_o[gc];
#pragma unroll
      for (int r = 0; r < 4; ++r) {
        size_t off = (size_t)(gr + r) * HID_D + gc;
        out[off] = acc[ii][j][r] + bv + x[off];
      }
    }
  }
}

// ---- vectorized RoPE via trig table (blocks 0..2303) + V transpose (2304..2559) ----
// One thread per (t, head, 8-dim group): u16x8 loads/stores, 64B table reads.
// q-heads and k-heads are contiguous in qkv_bf, so head*HD addresses both.
__global__ __launch_bounds__(256) void ropevt_kernel(const unsigned short* __restrict__ qkvb,
                                                     const float2* __restrict__ rtab,
                                                     unsigned short* __restrict__ qb,
                                                     unsigned short* __restrict__ kb,
                                                     unsigned short* __restrict__ vt) {
  __shared__ unsigned short tile[64][72];
  if (blockIdx.x >= ROPE_BLKS) {
    const int vb = blockIdx.x - ROPE_BLKS;
    const int g = vb >> 5;
    const int t0 = (vb & 31) << 6;
    const int r = threadIdx.x >> 3;
    const int c8 = (threadIdx.x & 7) << 3;
    const size_t vbase = (size_t)(NH + NKV) * HD + (size_t)g * HD;
#pragma unroll
    for (int hh = 0; hh < 2; ++hh) {
      int row = r + hh * 32;
      *(u16x8*)&tile[row][c8] =
          *(const u16x8*)(qkvb + (size_t)(t0 + row) * QKV_N + vbase + c8);
    }
    __syncthreads();
    const int d = threadIdx.x >> 2;
    const int ts = (threadIdx.x & 3) << 4;
    u16x8 v0, v1;
#pragma unroll
    for (int i = 0; i < 8; ++i) { v0[i] = tile[ts + i][d]; v1[i] = tile[ts + 8 + i][d]; }
    unsigned short* dst = vt + (size_t)(g * HD + d) * T_SEQ + t0 + ts;
    *(u16x8*)dst = v0;
    *(u16x8*)(dst + 8) = v1;
    return;
  }
  const int idx = blockIdx.x * 256 + threadIdx.x;     // < 2048*72*4
  const int d8 = (idx & 3) << 3;                      // 0,8,16,24
  const int head = (idx >> 2) % (NH + NKV);
  const int t = idx / ((NH + NKV) * 4);
  const unsigned short* b = qkvb + (size_t)t * QKV_N + head * HD + d8;
  u16x8 x1v = *(const u16x8*)b;
  u16x8 x2v = *(const u16x8*)(b + 32);
  const float2* cs = rtab + t * 32 + d8;
  u16x8 o1, o2;
#pragma unroll
  for (int j = 0; j < 8; ++j) {
    float x1 = bf2f(x1v[j]), x2 = bf2f(x2v[j]);
    float2 c = cs[j];
    o1[j] = f2bf(x1 * c.x - x2 * c.y);
    o2[j] = f2bf(x2 * c.x + x1 * c.y);
  }
  unsigned short* ob;
  if (head < NH) ob = qb + (size_t)t * ATT_N + head * HD + d8;
  else           ob = kb + (size_t)t * (NKV * HD) + (head - NH) * HD + d8;
  *(u16x8*)ob = o1;
  *(u16x8*)(ob + 32) = o2;
}

// ---------------- attention + uniformly-distributed w_o->bf16 conversion ----------------
__global__ __launch_bounds__(256) void attn_kernel(const unsigned short* __restrict__ qb,
                                                   const unsigned short* __restrict__ kb,
                                                   const unsigned short* __restrict__ vt,
                                                   const float* __restrict__ sinks,
                                                   unsigned short* __restrict__ att,
                                                   const float* __restrict__ wo_src,
                                                   unsigned short* __restrict__ wo_dst) {
  __shared__ unsigned short orep[4][16][72];
  {
    const int bid = blockIdx.y * gridDim.x + blockIdx.x;
    const int total = HID_D * 1024;
    for (int i = bid * 256 + threadIdx.x; i < total; i += 2048 * 256) {
      float4 v = ((const float4*)wo_src)[i];
      u16x4 o = { f2bf(v.x), f2bf(v.y), f2bf(v.z), f2bf(v.w) };
      ((u16x4*)wo_dst)[i] = o;
    }
  }
  const int lane = threadIdx.x & 63;
  const int wid = threadIdx.x >> 6;
  const int q0 = blockIdx.x * 16;
  const int h = blockIdx.y * 4 + wid;
  const int g = h >> 3;
  const int lq = lane & 15;
  const int ro = lane >> 4;

  bf16x8 bq0, bq1;
  {
    const unsigned short* qp = qb + (size_t)(q0 + lq) * ATT_N + h * HD + ro * 8;
    bq0 = *(const bf16x8*)qp;
    bq1 = *(const bf16x8*)(qp + 32);
  }
  float m_run = sinks[h];
  float l_run = 1.0f;
  f32x4 o0 = {0.f, 0.f, 0.f, 0.f}, o1 = o0, o2 = o0, o3 = o0;
  const int qg = q0 + lq;
  const int jstart = (q0 >= WIN) ? q0 - WIN : 0;

  for (int jt = jstart; jt <= q0; jt += 32) {
    f32x4 st0 = {0.f, 0.f, 0.f, 0.f}, st1 = st0;
    {
      int kr = jt + ((lq >> 2) << 3) + (lq & 3);
      int kr0 = min(kr, T_SEQ - 1);
      int kr1 = min(kr + 4, T_SEQ - 1);
      const unsigned short* kp0 = kb + (size_t)kr0 * (NKV * HD) + g * HD + ro * 8;
      const unsigned short* kp1 = kb + (size_t)kr1 * (NKV * HD) + g * HD + ro * 8;
      bf16x8 ka0a = *(const bf16x8*)kp0;
      bf16x8 ka0b = *(const bf16x8*)(kp0 + 32);
      bf16x8 ka1a = *(const bf16x8*)kp1;
      bf16x8 ka1b = *(const bf16x8*)(kp1 + 32);
      st0 = __builtin_amdgcn_mfma_f32_16x16x32_bf16(ka0a, bq0, st0, 0, 0, 0);
      st0 = __builtin_amdgcn_mfma_f32_16x16x32_bf16(ka0b, bq1, st0, 0, 0, 0);
      st1 = __builtin_amdgcn_mfma_f32_16x16x32_bf16(ka1a, bq0, st1, 0, 0, 0);
      st1 = __builtin_amdgcn_mfma_f32_16x16x32_bf16(ka1b, bq1, st1, 0, 0, 0);
    }
    float p[8];
    float tmax = -3.0e30f;
#pragma unroll
    for (int r = 0; r < 4; ++r) {
      int jg0 = jt + ro * 8 + r;
      int jg1 = jg0 + 4;
      float s0 = (jg0 <= qg && (qg - jg0) < WIN) ? st0[r] * RSCALE : -3.0e30f;
      float s1 = (jg1 <= qg && (qg - jg1) < WIN) ? st1[r] * RSCALE : -3.0e30f;
      p[r] = s0;
      p[r + 4] = s1;
      tmax = fmaxf(tmax, fmaxf(s0, s1));
    }
    tmax = fmaxf(tmax, __shfl_xor(tmax, 16));
    tmax = fmaxf(tmax, __shfl_xor(tmax, 32));
    float m_new = fmaxf(m_run, tmax);
    float rescale = expf(m_run - m_new);
    float psum = 0.f;
    bf16x8 pa;
#pragma unroll
    for (int jj = 0; jj < 8; ++jj) {
      float pe = expf(p[jj] - m_new);
      psum += pe;
      pa[jj] = (short)f2bf(pe);
    }
    psum += __shfl_xor(psum, 16);
    psum += __shfl_xor(psum, 32);
    l_run = l_run * rescale + psum;
    m_run = m_new;
    f32x4 rs4;
#pragma unroll
    for (int r = 0; r < 4; ++r) rs4[r] = __shfl(rescale, ro * 4 + r);
    o0 *= rs4; o1 *= rs4; o2 *= rs4; o3 *= rs4;
    int tb = jt + ro * 8;
    if (tb > T_SEQ - 8) tb = T_SEQ - 8;
    const unsigned short* vp = vt + (size_t)(g * HD + lq) * T_SEQ + tb;
    bf16x8 v0 = *(const bf16x8*)vp;
    bf16x8 v1 = *(const bf16x8*)(vp + 16 * T_SEQ);
    bf16x8 v2 = *(const bf16x8*)(vp + 32 * T_SEQ);
    bf16x8 v3 = *(const bf16x8*)(vp + 48 * T_SEQ);
    o0 = __builtin_amdgcn_mfma_f32_16x16x32_bf16(pa, v0, o0, 0, 0, 0);
    o1 = __builtin_amdgcn_mfma_f32_16x16x32_bf16(pa, v1, o1, 0, 0, 0);
    o2 = __builtin_amdgcn_mfma_f32_16x16x32_bf16(pa, v2, o2, 0, 0, 0);
    o3 = __builtin_amdgcn_mfma_f32_16x16x32_bf16(pa, v3, o3, 0, 0, 0);
  }

#pragma unroll
  for (int r = 0; r < 4; ++r) {
    float lr = __shfl(l_run, ro * 4 + r);
    float inv = 1.0f / lr;
    int row = ro * 4 + r;
    orep[wid][row][lq]      = f2bf(o0[r] * inv);
    orep[wid][row][lq + 16] = f2bf(o1[r] * inv);
    orep[wid][row][lq + 32] = f2bf(o2[r] * inv);
    orep[wid][row][lq + 48] = f2bf(o3[r] * inv);
  }
  {
    const int row = lane >> 2;
    const int seg = (lane & 3) << 4;
    u16x8 w0 = *(const u16x8*)&orep[wid][row][seg];
    u16x8 w1 = *(const u16x8*)&orep[wid][row][seg + 8];
    unsigned short* op = att + (size_t)(q0 + row) * ATT_N + h * HD + seg;
    *(u16x8*)op = w0;
    *(u16x8*)(op + 8) = w1;
  }
}

extern "C" void kernel_launch(void* const* d_in, const int* in_sizes, int n_in,
                              void* d_out, int out_size, void* d_ws, size_t ws_size,
                              hipStream_t stream) {
  const float* x = (const float*)d_in[0];
  const int* pos = (const int*)d_in[1];
  const float* norm_w = (const float*)d_in[2];
  const float* w_qkv = (const float*)d_in[3];
  const float* b_qkv = (const float*)d_in[4];
  const float* w_o = (const float*)d_in[5];
  const float* b_o = (const float*)d_in[6];
  const float* sinks = (const float*)d_in[7];
  float* out = (float*)d_out;

  unsigned short* t_bf = (unsigned short*)d_ws;                        // [2048][2944]
  unsigned short* wq_bf = t_bf + (size_t)T_SEQ * KPAD;                 // [5120][2944]
  unsigned short* wo_bf = wq_bf + (size_t)QKV_N * KPAD;                // [2880][4096] (region sized NOPAD)
  unsigned short* qkv_bf = wo_bf + (size_t)NOPAD * ATT_N;              // [2048][5120] bf16
  unsigned short* qb = qkv_bf + (size_t)T_SEQ * QKV_N;                 // [2048][4096]
  unsigned short* kb = qb + (size_t)T_SEQ * ATT_N;                     // [2048][512]
  unsigned short* vt = kb + (size_t)T_SEQ * NKV * HD;                  // [8][64][2048]
  unsigned short* att = vt + (size_t)NKV * HD * T_SEQ;                 // [2048][4096]
  float2* rtab = (float2*)(att + (size_t)T_SEQ * ATT_N);               // [2048][32] (cos,sin)

  // 1. RMSNorm + w_qkv conversion + RoPE trig table
  pre_kernel<<<3136, 256, 0, stream>>>(x, norm_w, t_bf, w_qkv, wq_bf, pos, rtab);
  // 2. QKV GEMM: 128x320, 256 blocks (full chip)
  qkv320_kernel<<<256, 512, 0, stream>>>(t_bf, wq_bf, qkv_bf, b_qkv);
  // 3. RoPE (vectorized, table-driven) + V transpose, one launch
  ropevt_kernel<<<ROPE_BLKS + 256, 256, 0, stream>>>(qkv_bf, rtab, qb, kb, vt);
  // 4. attention + distributed w_o conversion (must precede outproj)
  attn_kernel<<<dim3(T_SEQ / 16, NH / 4), 256, 0, stream>>>(qb, kb, vt, sinks, att, w_o, wo_bf);
  // 5. out projection: single-phase 3-buf 128x192 tiles, counted vmcnt(5), 240 blocks
  outproj192_kernel<<<240, 512, 0, stream>>>(att, wo_bf, out, b_o, x);
}